// Round 2
// baseline (3393.867 us; speedup 1.0000x reference)
//
#include <hip/hip_runtime.h>
#include <hip/hip_bf16.h>

#define TILE 64
#define TK 16

// C = alpha * A * op(B); A is MxK row-major (lda), C is MxN (ldc).
// BT=true:  B is NxK row-major (ldb) -> C[m,n] = sum_k A[m,k]*B[n,k]
// BT=false: B is KxN row-major (ldb) -> C[m,n] = sum_k A[m,k]*B[k,n]
// Batched over blockIdx.z with element strides sA,sB,sC.
// Requires: M%64==0, N%64==0, K%16==0.
template<bool BT>
__global__ __launch_bounds__(256)
void gemm_f32(const float* __restrict__ A, int lda, long sA,
              const float* __restrict__ B, int ldb, long sB,
              float* __restrict__ C, int ldc, long sC,
              int M, int N, int Kd, float alpha)
{
    long bz = blockIdx.z;
    A += bz * sA; B += bz * sB; C += bz * sC;
    int m0 = blockIdx.y * TILE, n0 = blockIdx.x * TILE;
    __shared__ float As[TK][TILE + 4];
    __shared__ float Bs[TK][TILE + 4];
    int tid = threadIdx.x;
    int tm = (tid >> 4) * 4;   // 0..60
    int tn = (tid & 15) * 4;   // 0..60
    float acc[4][4] = {};
    for (int k0 = 0; k0 < Kd; k0 += TK) {
        {
            int kk = tid & 15;
            int m  = tid >> 4;
            #pragma unroll
            for (int mm = 0; mm < 4; ++mm)
                As[kk][m + mm * 16] = A[(long)(m0 + m + mm * 16) * lda + k0 + kk];
        }
        if (BT) {
            int kk = tid & 15;
            int n  = tid >> 4;
            #pragma unroll
            for (int nn = 0; nn < 4; ++nn)
                Bs[kk][n + nn * 16] = B[(long)(n0 + n + nn * 16) * ldb + k0 + kk];
        } else {
            int n  = tid & 63;
            int kk = tid >> 6;
            #pragma unroll
            for (int k2 = 0; k2 < 4; ++k2)
                Bs[kk + k2 * 4][n] = B[(long)(k0 + kk + k2 * 4) * ldb + n0 + n];
        }
        __syncthreads();
        #pragma unroll
        for (int kk = 0; kk < TK; ++kk) {
            float4 a4 = *reinterpret_cast<const float4*>(&As[kk][tm]);
            float4 b4 = *reinterpret_cast<const float4*>(&Bs[kk][tn]);
            float a[4] = {a4.x, a4.y, a4.z, a4.w};
            float b[4] = {b4.x, b4.y, b4.z, b4.w};
            #pragma unroll
            for (int i = 0; i < 4; ++i)
                #pragma unroll
                for (int j = 0; j < 4; ++j)
                    acc[i][j] += a[i] * b[j];
        }
        __syncthreads();
    }
    #pragma unroll
    for (int i = 0; i < 4; ++i)
        #pragma unroll
        for (int j = 0; j < 4; ++j)
            C[(long)(m0 + tm + i) * ldc + n0 + tn + j] = alpha * acc[i][j];
}

// RoPE applied in-place to q and k buffers laid out [S][HID] (head h = cols h*128..h*128+127).
__global__ __launch_bounds__(256)
void rope_kernel(float* __restrict__ q, float* __restrict__ k, const int* __restrict__ pos)
{
    int i = blockIdx.x * 256 + threadIdx.x;  // over S*H*64
    if (i >= 1024 * 32 * 64) return;
    int d   = i & 63;
    int rem = i >> 6;
    int h   = rem & 31;
    int s   = rem >> 5;
    float p = (float)pos[s];
    // inv_freq = 10000^(-d/64) = 2^(-d/64 * log2(10000))
    float inv = exp2f(-(float)d * (13.287712379549449f / 64.0f));
    float ang = p * inv;
    float c = cosf(ang), sn = sinf(ang);
    long base = ((long)s * 4096) + h * 128 + d;
    float x1 = q[base], x2 = q[base + 64];
    q[base]      = x1 * c - x2 * sn;
    q[base + 64] = x2 * c + x1 * sn;
    x1 = k[base]; x2 = k[base + 64];
    k[base]      = x1 * c - x2 * sn;
    k[base + 64] = x2 * c + x1 * sn;
}

// Per-row layernorm over last axis (1024). y = (x-mean)*rsqrt(var+eps)*w[c]+b[c]
__global__ __launch_bounds__(256)
void ln_rows(const float* __restrict__ x, float* __restrict__ y,
             const float* __restrict__ w, const float* __restrict__ b)
{
    long row = blockIdx.x;
    const float* xr = x + row * 1024;
    float* yr = y + row * 1024;
    __shared__ float sb[8];
    float v[4];
    float s = 0.f, ss = 0.f;
    #pragma unroll
    for (int i = 0; i < 4; ++i) {
        v[i] = xr[threadIdx.x + i * 256];
        s += v[i]; ss += v[i] * v[i];
    }
    #pragma unroll
    for (int off = 32; off; off >>= 1) {
        s  += __shfl_down(s, off, 64);
        ss += __shfl_down(ss, off, 64);
    }
    int wid = threadIdx.x >> 6, lane = threadIdx.x & 63;
    if (!lane) { sb[wid] = s; sb[4 + wid] = ss; }
    __syncthreads();
    s  = sb[0] + sb[1] + sb[2] + sb[3];
    ss = sb[4] + sb[5] + sb[6] + sb[7];
    float mean = s * (1.f / 1024.f);
    float var  = ss * (1.f / 1024.f) - mean * mean;
    float inv  = rsqrtf(var + 1e-5f);
    #pragma unroll
    for (int i = 0; i < 4; ++i) {
        int c = threadIdx.x + i * 256;
        yr[c] = (v[i] - mean) * inv * w[c] + b[c];
    }
}

// est[row] = sum_k attn[row,k]*sw[k] + sbias[0]
__global__ __launch_bounds__(256)
void est_kernel(const float* __restrict__ attn, const float* __restrict__ sw,
                const float* __restrict__ sbias, float* __restrict__ est)
{
    long row = blockIdx.x;
    const float* xr = attn + row * 1024;
    __shared__ float sb[4];
    float s = 0.f;
    #pragma unroll
    for (int i = 0; i < 4; ++i) {
        int c = threadIdx.x + i * 256;
        s += xr[c] * sw[c];
    }
    #pragma unroll
    for (int off = 32; off; off >>= 1) s += __shfl_down(s, off, 64);
    if (!(threadIdx.x & 63)) sb[threadIdx.x >> 6] = s;
    __syncthreads();
    if (threadIdx.x == 0) est[row] = sb[0] + sb[1] + sb[2] + sb[3] + sbias[0];
}

// Causal depthwise conv along q: y[h,q,k] = relu(bias + sum_t w[t]*x[h,q-62+t,k])
// Block: 256 threads = 64 k-cols x 4 q-rows; tile 64q x 64k; LDS stages 126x64.
// h0: global index of the first head in this chunk (for weight lookup).
__global__ __launch_bounds__(256)
void conv_kernel(const float* __restrict__ x, float* __restrict__ y,
                 const float* __restrict__ cw, const float* __restrict__ cb,
                 int layer, int h0)
{
    const int S = 1024;
    int h  = blockIdx.z;           // chunk-local head
    int hg = h0 + h;               // global head
    int q0 = blockIdx.y * 64;
    int k0 = blockIdx.x * 64;
    __shared__ float Ls[126][64];
    __shared__ float ws[63];
    int tid = threadIdx.x;
    if (tid < 63) ws[tid] = cw[(layer * 32 + hg) * 63 + tid];
    float bias = cb[layer * 32 + hg];
    int c  = tid & 63;
    int r0 = tid >> 6;
    const float* xh = x + (long)h * S * S;
    for (int r = r0; r < 126; r += 4) {
        int g = q0 - 62 + r;
        Ls[r][c] = (g >= 0) ? xh[(long)g * S + k0 + c] : 0.f;
    }
    __syncthreads();
    float* yh = y + (long)h * S * S;
    #pragma unroll 1
    for (int qi = r0; qi < 64; qi += 4) {
        float acc = bias;
        #pragma unroll
        for (int t = 0; t < 63; ++t)
            acc += ws[t] * Ls[qi + t][c];
        yh[(long)(q0 + qi) * S + k0 + c] = fmaxf(acc, 0.f);
    }
}

// In-place masked softmax over k, scaled by sigmoid(est). rows = chunk_heads*S.
__global__ __launch_bounds__(256)
void softmax_kernel(float* __restrict__ x, const float* __restrict__ mask,
                    const float* __restrict__ est)
{
    const int S = 1024;
    long row = blockIdx.x;            // h_local*S + q
    int q = (int)(row & (S - 1));
    float* xr = x + row * S;
    const float* mrow = mask + (long)q * S;
    __shared__ float sb[4];
    float v[4];
    float mx = -3.4028235e38f;
    #pragma unroll
    for (int i = 0; i < 4; ++i) {
        int c = threadIdx.x + i * 256;
        float t = xr[c] + mrow[c];
        t = fmaxf(t, -3.4028235e38f);
        v[i] = t;
        mx = fmaxf(mx, t);
    }
    #pragma unroll
    for (int off = 32; off; off >>= 1) mx = fmaxf(mx, __shfl_down(mx, off, 64));
    int wid = threadIdx.x >> 6, lane = threadIdx.x & 63;
    if (!lane) sb[wid] = mx;
    __syncthreads();
    mx = fmaxf(fmaxf(sb[0], sb[1]), fmaxf(sb[2], sb[3]));
    __syncthreads();
    float s = 0.f;
    #pragma unroll
    for (int i = 0; i < 4; ++i) { v[i] = expf(v[i] - mx); s += v[i]; }
    #pragma unroll
    for (int off = 32; off; off >>= 1) s += __shfl_down(s, off, 64);
    if (!lane) sb[wid] = s;
    __syncthreads();
    s = sb[0] + sb[1] + sb[2] + sb[3];
    float e = est[row];
    float sc = (1.f / (1.f + expf(-e))) / s;
    #pragma unroll
    for (int i = 0; i < 4; ++i) xr[threadIdx.x + i * 256] = v[i] * sc;
}

extern "C" void kernel_launch(void* const* d_in, const int* in_sizes, int n_in,
                              void* d_out, int out_size, void* d_ws, size_t ws_size,
                              hipStream_t stream) {
    const int S = 1024, H = 32, HID = 4096, DH = 128, DL = 64;

    const float* hs   = (const float*)d_in[0];
    const float* mask = (const float*)d_in[1];
    const int*   pos  = (const int*)d_in[2];
    const float* Wq   = (const float*)d_in[3];
    const float* Wk   = (const float*)d_in[4];
    const float* Wv   = (const float*)d_in[5];
    const float* Wo   = (const float*)d_in[6];
    const float* Wdq  = (const float*)d_in[7];
    const float* Wdk  = (const float*)d_in[8];
    const float* ln1w = (const float*)d_in[9];
    const float* ln1b = (const float*)d_in[10];
    const float* ln2w = (const float*)d_in[11];
    const float* ln2b = (const float*)d_in[12];
    const float* cw   = (const float*)d_in[13];
    const float* cb   = (const float*)d_in[14];
    const float* sw   = (const float*)d_in[15];
    const float* sbia = (const float*)d_in[16];
    float* out = (float*)d_out;

    // ---- workspace layout (adaptive to ws_size) ----
    // fixed: qb,kb,vb [S*HID] each, ql,kl [H*S*DL], est [H*S]  = 67.2 MB
    // ao aliases qb (qb dead after down-proj; pipeline is sequential on one stream)
    // chunk: two score buffers of CH*S*S floats each
    float* p   = (float*)d_ws;
    float* qb  = p; p += (long)S * HID;
    float* kb  = p; p += (long)S * HID;
    float* vb  = p; p += (long)S * HID;
    float* ql  = p; p += (long)H * S * DL;
    float* kl  = p; p += (long)H * S * DL;
    float* est = p; p += (long)H * S;
    float* ao  = qb;                       // alias (safe: qb unused after down-proj)

    long wsFloats  = (long)(ws_size / 4);
    long usedFixed = p - (float*)d_ws;
    long perHead   = 2L * S * S;           // ping + pong
    int CH = (int)((wsFloats - usedFixed) / perHead);
    if (CH > H) CH = H;
    if (CH < 1) CH = 1;                    // needs >= 75 MB total workspace
    float* sc0 = p;
    float* sc1 = sc0 + (long)CH * S * S;

    dim3 blk(256);

    // QKV projections: [S,HID] = hs[S,HID] @ W^T
    gemm_f32<true><<<dim3(HID / 64, S / 64, 1), blk, 0, stream>>>(hs, HID, 0, Wq, HID, 0, qb, HID, 0, S, HID, HID, 1.f);
    gemm_f32<true><<<dim3(HID / 64, S / 64, 1), blk, 0, stream>>>(hs, HID, 0, Wk, HID, 0, kb, HID, 0, S, HID, HID, 1.f);
    gemm_f32<true><<<dim3(HID / 64, S / 64, 1), blk, 0, stream>>>(hs, HID, 0, Wv, HID, 0, vb, HID, 0, S, HID, HID, 1.f);

    rope_kernel<<<(S * H * 64 + 255) / 256, blk, 0, stream>>>(qb, kb, pos);

    // low-rank down-proj per head: ql[h,s,e] = sum_d q[h,s,d]*Wdq[e,d]
    gemm_f32<true><<<dim3(1, S / 64, H), blk, 0, stream>>>(qb, HID, 128, Wdq, DH, 0, ql, DL, (long)S * DL, S, DL, DH, 1.f);
    gemm_f32<true><<<dim3(1, S / 64, H), blk, 0, stream>>>(kb, HID, 128, Wdk, DH, 0, kl, DL, (long)S * DL, S, DL, DH, 1.f);

    // per-head-chunk score pipeline
    for (int c0 = 0; c0 < H; c0 += CH) {
        int ch = (c0 + CH <= H) ? CH : (H - c0);

        // scores: sc0[hl,q,k] = ql[c0+hl,q,:].kl[c0+hl,k,:] / 8
        gemm_f32<true><<<dim3(S / 64, S / 64, ch), blk, 0, stream>>>(
            ql + (long)c0 * S * DL, DL, (long)S * DL,
            kl + (long)c0 * S * DL, DL, (long)S * DL,
            sc0, S, (long)S * S, S, S, DL, 0.125f);

        // est scale from raw (scaled) scores
        est_kernel<<<ch * S, blk, 0, stream>>>(sc0, sw, sbia, est + (long)c0 * S);

        // CNN score predictor: LN -> conv x3 -> LN
        ln_rows<<<ch * S, blk, 0, stream>>>(sc0, sc1, ln1w, ln1b);
        conv_kernel<<<dim3(16, 16, ch), blk, 0, stream>>>(sc1, sc0, cw, cb, 0, c0);
        conv_kernel<<<dim3(16, 16, ch), blk, 0, stream>>>(sc0, sc1, cw, cb, 1, c0);
        conv_kernel<<<dim3(16, 16, ch), blk, 0, stream>>>(sc1, sc0, cw, cb, 2, c0);
        ln_rows<<<ch * S, blk, 0, stream>>>(sc0, sc1, ln2w, ln2b);

        // mask + softmax + sigmoid(est) gate, in place on sc1
        softmax_kernel<<<ch * S, blk, 0, stream>>>(sc1, mask, est + (long)c0 * S);

        // out_h = p @ v  -> ao[S][HID] columns of this head chunk
        gemm_f32<false><<<dim3(DH / 64, S / 64, ch), blk, 0, stream>>>(
            sc1, S, (long)S * S,
            vb + (long)c0 * 128, HID, 128,
            ao + (long)c0 * 128, HID, 128,
            S, DH, S, 1.f);
    }

    // final: out = ao @ Wo^T
    gemm_f32<true><<<dim3(HID / 64, S / 64, 1), blk, 0, stream>>>(ao, HID, 0, Wo, HID, 0, out, HID, 0, S, HID, HID, 1.f);
}

// Round 4
// 2131.405 us; speedup vs baseline: 1.5923x; 1.5923x over previous
//
#include <hip/hip_runtime.h>
#include <hip/hip_bf16.h>

typedef __attribute__((ext_vector_type(8))) short bf16x8;
typedef __attribute__((ext_vector_type(4))) float f32x4;

#define TILE 64
#define TK 16

// round-to-nearest-even f32 -> bf16 bits
__device__ inline short f2bf(float x) {
    unsigned u = __float_as_uint(x);
    unsigned r = (u + 0x7fffu + ((u >> 16) & 1u)) >> 16;
    return (short)r;
}
__device__ inline float bf2f(short h) {
    return __uint_as_float(((unsigned)(unsigned short)h) << 16);
}

// ---------------- fp32 VALU GEMM (down-proj only) ----------------
template<bool BT>
__global__ __launch_bounds__(256)
void gemm_f32(const float* __restrict__ A, int lda, long sA,
              const float* __restrict__ B, int ldb, long sB,
              float* __restrict__ C, int ldc, long sC,
              int M, int N, int Kd, float alpha)
{
    long bz = blockIdx.z;
    A += bz * sA; B += bz * sB; C += bz * sC;
    int m0 = blockIdx.y * TILE, n0 = blockIdx.x * TILE;
    __shared__ float As[TK][TILE + 4];
    __shared__ float Bs[TK][TILE + 4];
    int tid = threadIdx.x;
    int tm = (tid >> 4) * 4;
    int tn = (tid & 15) * 4;
    float acc[4][4] = {};
    for (int k0 = 0; k0 < Kd; k0 += TK) {
        {
            int kk = tid & 15;
            int m  = tid >> 4;
            #pragma unroll
            for (int mm = 0; mm < 4; ++mm)
                As[kk][m + mm * 16] = A[(long)(m0 + m + mm * 16) * lda + k0 + kk];
        }
        if (BT) {
            int kk = tid & 15;
            int n  = tid >> 4;
            #pragma unroll
            for (int nn = 0; nn < 4; ++nn)
                Bs[kk][n + nn * 16] = B[(long)(n0 + n + nn * 16) * ldb + k0 + kk];
        } else {
            int n  = tid & 63;
            int kk = tid >> 6;
            #pragma unroll
            for (int k2 = 0; k2 < 4; ++k2)
                Bs[kk + k2 * 4][n] = B[(long)(k0 + kk + k2 * 4) * ldb + n0 + n];
        }
        __syncthreads();
        #pragma unroll
        for (int kk = 0; kk < TK; ++kk) {
            float4 a4 = *reinterpret_cast<const float4*>(&As[kk][tm]);
            float4 b4 = *reinterpret_cast<const float4*>(&Bs[kk][tn]);
            float a[4] = {a4.x, a4.y, a4.z, a4.w};
            float b[4] = {b4.x, b4.y, b4.z, b4.w};
            #pragma unroll
            for (int i = 0; i < 4; ++i)
                #pragma unroll
                for (int j = 0; j < 4; ++j)
                    acc[i][j] += a[i] * b[j];
        }
        __syncthreads();
    }
    #pragma unroll
    for (int i = 0; i < 4; ++i)
        #pragma unroll
        for (int j = 0; j < 4; ++j)
            C[(long)(m0 + tm + i) * ldc + n0 + tn + j] = alpha * acc[i][j];
}

// ---------------- MFMA GEMM on fp32 inputs: C = alpha * A * B^T ----------------
// A: MxK fp32 row-major (lda), B: NxK fp32 row-major (ldb), C: fp32 (ldc).
// Tiles are decomposed in-register to bf16 hi(+lo). SPLIT: 3-term product
// (hi*hi + hi*lo + lo*hi) for ~fp32-quality results; !SPLIT: hi only.
// 256 thr / 4 waves; 128x128 tile, BK=32; wave owns a 64x64 quadrant.
// Requires M%128==0, N%128==0, K%32==0, 16B-aligned rows.
#define LP 40   // LDS row pitch in shorts (padded from 32)
template<bool SPLIT>
__global__ __launch_bounds__(256)
void gemm_s(const float* __restrict__ A, int lda, long sA,
            const float* __restrict__ B, int ldb, long sB,
            float* __restrict__ C, int ldc, long sC,
            int Kd, float alpha)
{
    __shared__ short Ah[128][LP];
    __shared__ short Bh[128][LP];
    __shared__ short Al[SPLIT ? 128 : 1][LP];
    __shared__ short Bl[SPLIT ? 128 : 1][LP];
    long bz = blockIdx.z;
    A += bz * sA; B += bz * sB; C += bz * sC;
    int m0 = blockIdx.y * 128, n0 = blockIdx.x * 128;
    int tid  = threadIdx.x;
    int lane = tid & 63;
    int w    = tid >> 6;
    int wm   = w >> 1, wn = w & 1;
    int srow = tid >> 1;            // 0..127
    int scol = (tid & 1) * 16;      // 0 or 16
    int fr   = lane & 15;
    int kg   = (lane >> 4) * 8;
    f32x4 acc[4][4] = {};
    for (int k0 = 0; k0 < Kd; k0 += 32) {
        // ---- stage A and B tiles: fp32 -> bf16 hi/lo in LDS ----
        #pragma unroll
        for (int ab = 0; ab < 2; ++ab) {
            const float* src = ab ? (B + (long)(n0 + srow) * ldb + k0 + scol)
                                  : (A + (long)(m0 + srow) * lda + k0 + scol);
            short* dh = ab ? &Bh[srow][scol] : &Ah[srow][scol];
            short* dl = ab ? &Bl[SPLIT ? srow : 0][scol] : &Al[SPLIT ? srow : 0][scol];
            #pragma unroll
            for (int half = 0; half < 2; ++half) {
                float4 x0 = *reinterpret_cast<const float4*>(src + half * 8);
                float4 x1 = *reinterpret_cast<const float4*>(src + half * 8 + 4);
                float xs[8] = {x0.x, x0.y, x0.z, x0.w, x1.x, x1.y, x1.z, x1.w};
                bf16x8 hv, lv;
                #pragma unroll
                for (int j = 0; j < 8; ++j) {
                    short hb = f2bf(xs[j]);
                    hv[j] = hb;
                    if (SPLIT) lv[j] = f2bf(xs[j] - bf2f(hb));
                }
                *reinterpret_cast<bf16x8*>(dh + half * 8) = hv;
                if (SPLIT) *reinterpret_cast<bf16x8*>(dl + half * 8) = lv;
            }
        }
        __syncthreads();
        // ---- fragments + MFMA ----
        bf16x8 afh[4], bfh[4], afl[4], bfl[4];
        #pragma unroll
        for (int m = 0; m < 4; ++m)
            afh[m] = *(const bf16x8*)&Ah[wm * 64 + m * 16 + fr][kg];
        #pragma unroll
        for (int n = 0; n < 4; ++n)
            bfh[n] = *(const bf16x8*)&Bh[wn * 64 + n * 16 + fr][kg];
        if (SPLIT) {
            #pragma unroll
            for (int m = 0; m < 4; ++m)
                afl[m] = *(const bf16x8*)&Al[wm * 64 + m * 16 + fr][kg];
            #pragma unroll
            for (int n = 0; n < 4; ++n)
                bfl[n] = *(const bf16x8*)&Bl[wn * 64 + n * 16 + fr][kg];
        }
        #pragma unroll
        for (int m = 0; m < 4; ++m)
            #pragma unroll
            for (int n = 0; n < 4; ++n) {
                acc[m][n] = __builtin_amdgcn_mfma_f32_16x16x32_bf16(afh[m], bfh[n], acc[m][n], 0, 0, 0);
                if (SPLIT) {
                    acc[m][n] = __builtin_amdgcn_mfma_f32_16x16x32_bf16(afh[m], bfl[n], acc[m][n], 0, 0, 0);
                    acc[m][n] = __builtin_amdgcn_mfma_f32_16x16x32_bf16(afl[m], bfh[n], acc[m][n], 0, 0, 0);
                }
            }
        __syncthreads();
    }
    int crow0 = (lane >> 4) * 4;
    #pragma unroll
    for (int m = 0; m < 4; ++m)
        #pragma unroll
        for (int n = 0; n < 4; ++n)
            #pragma unroll
            for (int r = 0; r < 4; ++r)
                C[(long)(m0 + wm * 64 + m * 16 + crow0 + r) * ldc
                  + n0 + wn * 64 + n * 16 + fr] = alpha * acc[m][n][r];
}

// ---------------- v [S][4096] fp32 -> vT [H][128][1024] fp32 ----------------
__global__ __launch_bounds__(256)
void transpose_v(const float* __restrict__ v, float* __restrict__ vT)
{
    __shared__ float t[64][65];
    int h = blockIdx.z, s0 = blockIdx.x * 64, d0 = blockIdx.y * 64;
    int c = threadIdx.x & 63, r = threadIdx.x >> 6;
    for (int i = r; i < 64; i += 4)
        t[i][c] = v[(long)(s0 + i) * 4096 + h * 128 + d0 + c];
    __syncthreads();
    float* o = vT + ((long)h * 128 + d0) * 1024 + s0;
    for (int i = r; i < 64; i += 4)
        o[(long)i * 1024 + c] = t[c][i];
}

// ---------------- RoPE in place on q,k [S][4096] ----------------
__global__ __launch_bounds__(256)
void rope_kernel(float* __restrict__ q, float* __restrict__ k, const int* __restrict__ pos)
{
    int i = blockIdx.x * 256 + threadIdx.x;
    if (i >= 1024 * 32 * 64) return;
    int d   = i & 63;
    int rem = i >> 6;
    int h   = rem & 31;
    int s   = rem >> 5;
    float p = (float)pos[s];
    float inv = exp2f(-(float)d * (13.287712379549449f / 64.0f));
    float ang = p * inv;
    float c = cosf(ang), sn = sinf(ang);
    long base = ((long)s * 4096) + h * 128 + d;
    float x1 = q[base], x2 = q[base + 64];
    q[base]      = x1 * c - x2 * sn;
    q[base + 64] = x2 * c + x1 * sn;
    x1 = k[base]; x2 = k[base + 64];
    k[base]      = x1 * c - x2 * sn;
    k[base + 64] = x2 * c + x1 * sn;
}

// ---------------- row LayerNorm (1024) ----------------
__global__ __launch_bounds__(256)
void ln_rows(const float* __restrict__ x, float* __restrict__ y,
             const float* __restrict__ w, const float* __restrict__ b)
{
    long row = blockIdx.x;
    const float* xr = x + row * 1024;
    float* yr = y + row * 1024;
    __shared__ float sb[8];
    float v[4];
    float s = 0.f, ss = 0.f;
    #pragma unroll
    for (int i = 0; i < 4; ++i) {
        v[i] = xr[threadIdx.x + i * 256];
        s += v[i]; ss += v[i] * v[i];
    }
    #pragma unroll
    for (int off = 32; off; off >>= 1) {
        s  += __shfl_down(s, off, 64);
        ss += __shfl_down(ss, off, 64);
    }
    int wid = threadIdx.x >> 6, lane = threadIdx.x & 63;
    if (!lane) { sb[wid] = s; sb[4 + wid] = ss; }
    __syncthreads();
    s  = sb[0] + sb[1] + sb[2] + sb[3];
    ss = sb[4] + sb[5] + sb[6] + sb[7];
    float mean = s * (1.f / 1024.f);
    float var  = ss * (1.f / 1024.f) - mean * mean;
    float inv  = rsqrtf(var + 1e-5f);
    #pragma unroll
    for (int i = 0; i < 4; ++i) {
        int c = threadIdx.x + i * 256;
        yr[c] = (v[i] - mean) * inv * w[c] + b[c];
    }
}

// ---------------- est ----------------
__global__ __launch_bounds__(256)
void est_kernel(const float* __restrict__ attn, const float* __restrict__ sw,
                const float* __restrict__ sbias, float* __restrict__ est)
{
    long row = blockIdx.x;
    const float* xr = attn + row * 1024;
    __shared__ float sb[4];
    float s = 0.f;
    #pragma unroll
    for (int i = 0; i < 4; ++i) {
        int c = threadIdx.x + i * 256;
        s += xr[c] * sw[c];
    }
    #pragma unroll
    for (int off = 32; off; off >>= 1) s += __shfl_down(s, off, 64);
    if (!(threadIdx.x & 63)) sb[threadIdx.x >> 6] = s;
    __syncthreads();
    if (threadIdx.x == 0) est[row] = sb[0] + sb[1] + sb[2] + sb[3] + sbias[0];
}

// ---------------- causal depthwise conv + ReLU ----------------
__global__ __launch_bounds__(256)
void conv_kernel(const float* __restrict__ x, float* __restrict__ y,
                 const float* __restrict__ cw, const float* __restrict__ cb,
                 int layer, int h0)
{
    const int S = 1024;
    int h  = blockIdx.z;
    int hg = h0 + h;
    int q0 = blockIdx.y * 64;
    int k0 = blockIdx.x * 64;
    __shared__ float Ls[126][64];
    __shared__ float ws[63];
    int tid = threadIdx.x;
    if (tid < 63) ws[tid] = cw[(layer * 32 + hg) * 63 + tid];
    float bias = cb[layer * 32 + hg];
    int c  = tid & 63;
    int r0 = tid >> 6;
    const float* xh = x + (long)h * S * S;
    for (int r = r0; r < 126; r += 4) {
        int g = q0 - 62 + r;
        Ls[r][c] = (g >= 0) ? xh[(long)g * S + k0 + c] : 0.f;
    }
    __syncthreads();
    float* yh = y + (long)h * S * S;
    #pragma unroll 1
    for (int qi = r0; qi < 64; qi += 4) {
        float acc = bias;
        #pragma unroll
        for (int t = 0; t < 63; ++t)
            acc += ws[t] * Ls[qi + t][c];
        yh[(long)(q0 + qi) * S + k0 + c] = fmaxf(acc, 0.f);
    }
}

// ---------------- masked softmax * sigmoid(est), in place ----------------
__global__ __launch_bounds__(256)
void softmax_kernel(float* __restrict__ x, const float* __restrict__ mask,
                    const float* __restrict__ est)
{
    const int S = 1024;
    long row = blockIdx.x;
    int q = (int)(row & (S - 1));
    float* xr = x + row * S;
    const float* mrow = mask + (long)q * S;
    __shared__ float sb[4];
    float v[4];
    float mx = -3.4028235e38f;
    #pragma unroll
    for (int i = 0; i < 4; ++i) {
        int c = threadIdx.x + i * 256;
        float t = xr[c] + mrow[c];
        t = fmaxf(t, -3.4028235e38f);
        v[i] = t;
        mx = fmaxf(mx, t);
    }
    #pragma unroll
    for (int off = 32; off; off >>= 1) mx = fmaxf(mx, __shfl_down(mx, off, 64));
    int wid = threadIdx.x >> 6, lane = threadIdx.x & 63;
    if (!lane) sb[wid] = mx;
    __syncthreads();
    mx = fmaxf(fmaxf(sb[0], sb[1]), fmaxf(sb[2], sb[3]));
    __syncthreads();
    float s = 0.f;
    #pragma unroll
    for (int i = 0; i < 4; ++i) { v[i] = expf(v[i] - mx); s += v[i]; }
    #pragma unroll
    for (int off = 32; off; off >>= 1) s += __shfl_down(s, off, 64);
    if (!lane) sb[wid] = s;
    __syncthreads();
    s = sb[0] + sb[1] + sb[2] + sb[3];
    float e = est[row];
    float sc = (1.f / (1.f + expf(-e))) / s;
    #pragma unroll
    for (int i = 0; i < 4; ++i) xr[threadIdx.x + i * 256] = v[i] * sc;
}

extern "C" void kernel_launch(void* const* d_in, const int* in_sizes, int n_in,
                              void* d_out, int out_size, void* d_ws, size_t ws_size,
                              hipStream_t stream) {
    const int S = 1024, H = 32, HID = 4096, DH = 128, DL = 64;

    const float* hs   = (const float*)d_in[0];
    const float* mask = (const float*)d_in[1];
    const int*   pos  = (const int*)d_in[2];
    const float* Wq   = (const float*)d_in[3];
    const float* Wk   = (const float*)d_in[4];
    const float* Wv   = (const float*)d_in[5];
    const float* Wo   = (const float*)d_in[6];
    const float* Wdq  = (const float*)d_in[7];
    const float* Wdk  = (const float*)d_in[8];
    const float* ln1w = (const float*)d_in[9];
    const float* ln1b = (const float*)d_in[10];
    const float* ln2w = (const float*)d_in[11];
    const float* ln2b = (const float*)d_in[12];
    const float* cw   = (const float*)d_in[13];
    const float* cb   = (const float*)d_in[14];
    const float* sw   = (const float*)d_in[15];
    const float* sbia = (const float*)d_in[16];
    float* out = (float*)d_out;

    // ---- workspace (all fp32, round-2-proven layout) ----
    float* p   = (float*)d_ws;
    float* qb  = p; p += (long)S * HID;
    float* kb  = p; p += (long)S * HID;
    float* vb  = p; p += (long)S * HID;
    float* ql  = p; p += (long)H * S * DL;
    float* kl  = p; p += (long)H * S * DL;
    float* est = p; p += (long)H * S;
    float* ao  = qb;   // alias: qb dead after down-proj
    float* vT  = kb;   // alias: kb dead after down-proj

    long wsFloats  = (long)(ws_size / 4);
    long usedFixed = p - (float*)d_ws;
    long perHead   = 2L * S * S;
    int CH = (int)((wsFloats - usedFixed) / perHead);
    if (CH > H) CH = H;
    if (CH < 1) CH = 1;
    float* sc0 = p;
    float* sc1 = sc0 + (long)CH * S * S;

    dim3 blk(256);

    // q,k projections: split-bf16 MFMA (score path needs ~fp32 accuracy)
    gemm_s<true><<<dim3(HID / 128, S / 128, 1), blk, 0, stream>>>(hs, HID, 0, Wq, HID, 0, qb, HID, 0, HID, 1.f);
    gemm_s<true><<<dim3(HID / 128, S / 128, 1), blk, 0, stream>>>(hs, HID, 0, Wk, HID, 0, kb, HID, 0, HID, 1.f);
    // v projection: plain bf16 MFMA (value path tolerates bf16)
    gemm_s<false><<<dim3(HID / 128, S / 128, 1), blk, 0, stream>>>(hs, HID, 0, Wv, HID, 0, vb, HID, 0, HID, 1.f);

    rope_kernel<<<(S * H * 64 + 255) / 256, blk, 0, stream>>>(qb, kb, pos);

    // low-rank down-proj (fp32 VALU, exact)
    gemm_f32<true><<<dim3(1, S / 64, H), blk, 0, stream>>>(qb, HID, 128, Wdq, DH, 0, ql, DL, (long)S * DL, S, DL, DH, 1.f);
    gemm_f32<true><<<dim3(1, S / 64, H), blk, 0, stream>>>(kb, HID, 128, Wdk, DH, 0, kl, DL, (long)S * DL, S, DL, DH, 1.f);

    // v -> vT fp32 [H][128][1024] (into kb, now dead)
    transpose_v<<<dim3(S / 64, DH / 64, H), blk, 0, stream>>>(vb, vT);

    for (int c0 = 0; c0 < H; c0 += CH) {
        int ch = (c0 + CH <= H) ? CH : (H - c0);
        // scores = ql.kl^T / 8  (split-bf16: feeds LN amplification chain)
        gemm_s<true><<<dim3(S / 128, S / 128, ch), blk, 0, stream>>>(
            ql + (long)c0 * S * DL, DL, (long)S * DL,
            kl + (long)c0 * S * DL, DL, (long)S * DL,
            sc0, S, (long)S * S, DL, 0.125f);
        est_kernel<<<ch * S, blk, 0, stream>>>(sc0, sw, sbia, est + (long)c0 * S);
        ln_rows<<<ch * S, blk, 0, stream>>>(sc0, sc1, ln1w, ln1b);
        conv_kernel<<<dim3(16, 16, ch), blk, 0, stream>>>(sc1, sc0, cw, cb, 0, c0);
        conv_kernel<<<dim3(16, 16, ch), blk, 0, stream>>>(sc0, sc1, cw, cb, 1, c0);
        conv_kernel<<<dim3(16, 16, ch), blk, 0, stream>>>(sc1, sc0, cw, cb, 2, c0);
        ln_rows<<<ch * S, blk, 0, stream>>>(sc0, sc1, ln2w, ln2b);
        softmax_kernel<<<ch * S, blk, 0, stream>>>(sc1, mask, est + (long)c0 * S);
        // out_h = p @ v (plain bf16 MFMA; post-softmax errors don't amplify)
        gemm_s<false><<<dim3(1, S / 128, ch), blk, 0, stream>>>(
            sc1, S, (long)S * S,
            vT + (long)c0 * DH * S, S, (long)DH * S,
            ao + (long)c0 * 128, HID, 128,
            S, 1.f);
    }

    // final: out = ao @ Wo^T (plain bf16 MFMA)
    gemm_s<false><<<dim3(HID / 128, S / 128, 1), blk, 0, stream>>>(ao, HID, 0, Wo, HID, 0, out, HID, 0, HID, 1.f);
}

// Round 5
// 2039.604 us; speedup vs baseline: 1.6640x; 1.0450x over previous
//
#include <hip/hip_runtime.h>
#include <hip/hip_bf16.h>

typedef __attribute__((ext_vector_type(8))) short bf16x8;
typedef __attribute__((ext_vector_type(4))) float f32x4;

#define TILE 64
#define TK 16

// round-to-nearest-even f32 -> bf16 bits
__device__ inline short f2bf(float x) {
    unsigned u = __float_as_uint(x);
    unsigned r = (u + 0x7fffu + ((u >> 16) & 1u)) >> 16;
    return (short)r;
}
__device__ inline float bf2f(short h) {
    return __uint_as_float(((unsigned)(unsigned short)h) << 16);
}

// ---------------- fp32 VALU GEMM (down-proj only): C = A * B^T ----------------
template<bool BT>
__global__ __launch_bounds__(256)
void gemm_f32(const float* __restrict__ A, int lda, long sA,
              const float* __restrict__ B, int ldb, long sB,
              float* __restrict__ C, int ldc, long sC,
              int M, int N, int Kd, float alpha)
{
    long bz = blockIdx.z;
    A += bz * sA; B += bz * sB; C += bz * sC;
    int m0 = blockIdx.y * TILE, n0 = blockIdx.x * TILE;
    __shared__ float As[TK][TILE + 4];
    __shared__ float Bs[TK][TILE + 4];
    int tid = threadIdx.x;
    int tm = (tid >> 4) * 4;
    int tn = (tid & 15) * 4;
    float acc[4][4] = {};
    for (int k0 = 0; k0 < Kd; k0 += TK) {
        {
            int kk = tid & 15;
            int m  = tid >> 4;
            #pragma unroll
            for (int mm = 0; mm < 4; ++mm)
                As[kk][m + mm * 16] = A[(long)(m0 + m + mm * 16) * lda + k0 + kk];
        }
        {
            int kk = tid & 15;
            int n  = tid >> 4;
            #pragma unroll
            for (int nn = 0; nn < 4; ++nn)
                Bs[kk][n + nn * 16] = B[(long)(n0 + n + nn * 16) * ldb + k0 + kk];
        }
        __syncthreads();
        #pragma unroll
        for (int kk = 0; kk < TK; ++kk) {
            float4 a4 = *reinterpret_cast<const float4*>(&As[kk][tm]);
            float4 b4 = *reinterpret_cast<const float4*>(&Bs[kk][tn]);
            float a[4] = {a4.x, a4.y, a4.z, a4.w};
            float b[4] = {b4.x, b4.y, b4.z, b4.w};
            #pragma unroll
            for (int i = 0; i < 4; ++i)
                #pragma unroll
                for (int j = 0; j < 4; ++j)
                    acc[i][j] += a[i] * b[j];
        }
        __syncthreads();
    }
    #pragma unroll
    for (int i = 0; i < 4; ++i)
        #pragma unroll
        for (int j = 0; j < 4; ++j)
            C[(long)(m0 + tm + i) * ldc + n0 + tn + j] = alpha * acc[i][j];
}

// ---------------- m97-style bf16 MFMA GEMM: C (+)= alpha * A * B^T ----------------
// A: MxK bf16 row-major (lda), B: NxK bf16 row-major (ldb).
// CMODE 0: C fp32 =, 1: C fp32 +=, 2: C^T bf16 (CT[n][m], ldc = row length of CT)
// 256 thr / 4 waves; 128x128 tile, BK=32; wave owns 64x64 quadrant; global_load_lds staging.
__device__ inline void gld_lds16(const __hip_bfloat16* g, __hip_bfloat16* l)
{
    __builtin_amdgcn_global_load_lds(
        (const __attribute__((address_space(1))) unsigned int*)g,
        (__attribute__((address_space(3))) unsigned int*)l,
        16, 0, 0);
}

template<int CMODE>
__global__ __launch_bounds__(256)
void gemm16(const __hip_bfloat16* __restrict__ A, int lda, long sA,
            const __hip_bfloat16* __restrict__ B, int ldb, long sB,
            void* __restrict__ Cv, int ldc, long sC,
            int Kd, float alpha)
{
    __shared__ __hip_bfloat16 As[128][32];
    __shared__ __hip_bfloat16 Bs[128][32];
    long bz = blockIdx.z;
    A += bz * sA; B += bz * sB;
    int m0 = blockIdx.y * 128, n0 = blockIdx.x * 128;
    int tid  = threadIdx.x;
    int w    = tid >> 6, lane = tid & 63;
    int wm   = w >> 1,  wn   = w & 1;
    int lrow = lane >> 2;
    int lseg = (lane & 3) * 8;
    int fr   = lane & 15;
    int kg   = (lane >> 4) * 8;
    f32x4 acc[4][4] = {};
    for (int k0 = 0; k0 < Kd; k0 += 32) {
        #pragma unroll
        for (int i = 0; i < 2; ++i) {
            int r = w * 32 + i * 16;
            gld_lds16(&A[(long)(m0 + r + lrow) * lda + k0 + lseg], &As[r][0]);
            gld_lds16(&B[(long)(n0 + r + lrow) * ldb + k0 + lseg], &Bs[r][0]);
        }
        __syncthreads();
        bf16x8 af[4], bfr[4];
        #pragma unroll
        for (int m = 0; m < 4; ++m)
            af[m] = *(const bf16x8*)&As[wm * 64 + m * 16 + fr][kg];
        #pragma unroll
        for (int n = 0; n < 4; ++n)
            bfr[n] = *(const bf16x8*)&Bs[wn * 64 + n * 16 + fr][kg];
        #pragma unroll
        for (int m = 0; m < 4; ++m)
            #pragma unroll
            for (int n = 0; n < 4; ++n)
                acc[m][n] = __builtin_amdgcn_mfma_f32_16x16x32_bf16(af[m], bfr[n], acc[m][n], 0, 0, 0);
        __syncthreads();
    }
    int crow0 = (lane >> 4) * 4;
    if constexpr (CMODE == 2) {
        __hip_bfloat16* CT = (__hip_bfloat16*)Cv + bz * sC;
        #pragma unroll
        for (int m = 0; m < 4; ++m)
            #pragma unroll
            for (int n = 0; n < 4; ++n)
                #pragma unroll
                for (int r = 0; r < 4; ++r) {
                    int row = m0 + wm * 64 + m * 16 + crow0 + r;
                    int col = n0 + wn * 64 + n * 16 + fr;
                    CT[(long)col * ldc + row] = __float2bfloat16(alpha * acc[m][n][r]);
                }
    } else {
        float* C = (float*)Cv + bz * sC;
        #pragma unroll
        for (int m = 0; m < 4; ++m)
            #pragma unroll
            for (int n = 0; n < 4; ++n)
                #pragma unroll
                for (int r = 0; r < 4; ++r) {
                    long idx = (long)(m0 + wm * 64 + m * 16 + crow0 + r) * ldc
                             + n0 + wn * 64 + n * 16 + fr;
                    float v = alpha * acc[m][n][r];
                    if constexpr (CMODE == 1) v += C[idx];
                    C[idx] = v;
                }
    }
}

// ---------------- in-register split MFMA GEMM (QK^T): C = alpha * A * B^T ----------------
// fp32 inputs decomposed to bf16 hi/lo in LDS; 3-term product.
#define LP 40
__global__ __launch_bounds__(256)
void gemm_s(const float* __restrict__ A, int lda, long sA,
            const float* __restrict__ B, int ldb, long sB,
            float* __restrict__ C, int ldc, long sC,
            int Kd, float alpha)
{
    __shared__ short Ah[128][LP];
    __shared__ short Bh[128][LP];
    __shared__ short Al[128][LP];
    __shared__ short Bl[128][LP];
    long bz = blockIdx.z;
    A += bz * sA; B += bz * sB; C += bz * sC;
    int m0 = blockIdx.y * 128, n0 = blockIdx.x * 128;
    int tid  = threadIdx.x;
    int lane = tid & 63;
    int w    = tid >> 6;
    int wm   = w >> 1, wn = w & 1;
    int srow = tid >> 1;
    int scol = (tid & 1) * 16;
    int fr   = lane & 15;
    int kg   = (lane >> 4) * 8;
    f32x4 acc[4][4] = {};
    for (int k0 = 0; k0 < Kd; k0 += 32) {
        #pragma unroll
        for (int ab = 0; ab < 2; ++ab) {
            const float* src = ab ? (B + (long)(n0 + srow) * ldb + k0 + scol)
                                  : (A + (long)(m0 + srow) * lda + k0 + scol);
            short* dh = ab ? &Bh[srow][scol] : &Ah[srow][scol];
            short* dl = ab ? &Bl[srow][scol] : &Al[srow][scol];
            #pragma unroll
            for (int half = 0; half < 2; ++half) {
                float4 x0 = *reinterpret_cast<const float4*>(src + half * 8);
                float4 x1 = *reinterpret_cast<const float4*>(src + half * 8 + 4);
                float xs[8] = {x0.x, x0.y, x0.z, x0.w, x1.x, x1.y, x1.z, x1.w};
                bf16x8 hv, lv;
                #pragma unroll
                for (int j = 0; j < 8; ++j) {
                    short hb = f2bf(xs[j]);
                    hv[j] = hb;
                    lv[j] = f2bf(xs[j] - bf2f(hb));
                }
                *reinterpret_cast<bf16x8*>(dh + half * 8) = hv;
                *reinterpret_cast<bf16x8*>(dl + half * 8) = lv;
            }
        }
        __syncthreads();
        bf16x8 afh[4], bfh[4], afl[4], bfl[4];
        #pragma unroll
        for (int m = 0; m < 4; ++m) {
            afh[m] = *(const bf16x8*)&Ah[wm * 64 + m * 16 + fr][kg];
            afl[m] = *(const bf16x8*)&Al[wm * 64 + m * 16 + fr][kg];
        }
        #pragma unroll
        for (int n = 0; n < 4; ++n) {
            bfh[n] = *(const bf16x8*)&Bh[wn * 64 + n * 16 + fr][kg];
            bfl[n] = *(const bf16x8*)&Bl[wn * 64 + n * 16 + fr][kg];
        }
        #pragma unroll
        for (int m = 0; m < 4; ++m)
            #pragma unroll
            for (int n = 0; n < 4; ++n) {
                acc[m][n] = __builtin_amdgcn_mfma_f32_16x16x32_bf16(afh[m], bfh[n], acc[m][n], 0, 0, 0);
                acc[m][n] = __builtin_amdgcn_mfma_f32_16x16x32_bf16(afh[m], bfl[n], acc[m][n], 0, 0, 0);
                acc[m][n] = __builtin_amdgcn_mfma_f32_16x16x32_bf16(afl[m], bfh[n], acc[m][n], 0, 0, 0);
            }
        __syncthreads();
    }
    int crow0 = (lane >> 4) * 4;
    #pragma unroll
    for (int m = 0; m < 4; ++m)
        #pragma unroll
        for (int n = 0; n < 4; ++n)
            #pragma unroll
            for (int r = 0; r < 4; ++r)
                C[(long)(m0 + wm * 64 + m * 16 + crow0 + r) * ldc
                  + n0 + wn * 64 + n * 16 + fr] = alpha * acc[m][n][r];
}

// ---------------- f32 -> bf16 hi or lo part (n % 4 == 0) ----------------
struct alignas(8) s4 { short a, b, c, d; };
template<bool LO>
__global__ __launch_bounds__(256)
void cvt_part(const float* __restrict__ x, short* __restrict__ y, long n4)
{
    long i = (long)blockIdx.x * 256 + threadIdx.x;
    long stride = (long)gridDim.x * 256;
    for (; i < n4; i += stride) {
        float4 v = reinterpret_cast<const float4*>(x)[i];
        float xs[4] = {v.x, v.y, v.z, v.w};
        s4 o;
        short* op = &o.a;
        #pragma unroll
        for (int j = 0; j < 4; ++j) {
            short hb = f2bf(xs[j]);
            op[j] = LO ? f2bf(xs[j] - bf2f(hb)) : hb;
        }
        reinterpret_cast<s4*>(y)[i] = o;
    }
}

// ---------------- RoPE in place on q,k [S][4096] ----------------
__global__ __launch_bounds__(256)
void rope_kernel(float* __restrict__ q, float* __restrict__ k, const int* __restrict__ pos)
{
    int i = blockIdx.x * 256 + threadIdx.x;
    if (i >= 1024 * 32 * 64) return;
    int d   = i & 63;
    int rem = i >> 6;
    int h   = rem & 31;
    int s   = rem >> 5;
    float p = (float)pos[s];
    float inv = exp2f(-(float)d * (13.287712379549449f / 64.0f));
    float ang = p * inv;
    float c = cosf(ang), sn = sinf(ang);
    long base = ((long)s * 4096) + h * 128 + d;
    float x1 = q[base], x2 = q[base + 64];
    q[base]      = x1 * c - x2 * sn;
    q[base + 64] = x2 * c + x1 * sn;
    x1 = k[base]; x2 = k[base + 64];
    k[base]      = x1 * c - x2 * sn;
    k[base + 64] = x2 * c + x1 * sn;
}

// ---------------- fused est + LayerNorm1: sc0 -> sc1, est ----------------
__global__ __launch_bounds__(256)
void est_ln1(const float* __restrict__ x, float* __restrict__ y,
             const float* __restrict__ sw, const float* __restrict__ sbias,
             float* __restrict__ est,
             const float* __restrict__ w, const float* __restrict__ b)
{
    long row = blockIdx.x;
    const float* xr = x + row * 1024;
    float* yr = y + row * 1024;
    __shared__ float sb[12];
    float v[4];
    float s = 0.f, ss = 0.f, dt = 0.f;
    #pragma unroll
    for (int i = 0; i < 4; ++i) {
        int c = threadIdx.x + i * 256;
        v[i] = xr[c];
        s += v[i]; ss += v[i] * v[i]; dt += v[i] * sw[c];
    }
    #pragma unroll
    for (int off = 32; off; off >>= 1) {
        s  += __shfl_down(s, off, 64);
        ss += __shfl_down(ss, off, 64);
        dt += __shfl_down(dt, off, 64);
    }
    int wid = threadIdx.x >> 6, lane = threadIdx.x & 63;
    if (!lane) { sb[wid] = s; sb[4 + wid] = ss; sb[8 + wid] = dt; }
    __syncthreads();
    s  = sb[0] + sb[1] + sb[2] + sb[3];
    ss = sb[4] + sb[5] + sb[6] + sb[7];
    if (threadIdx.x == 0) est[row] = sb[8] + sb[9] + sb[10] + sb[11] + sbias[0];
    float mean = s * (1.f / 1024.f);
    float var  = ss * (1.f / 1024.f) - mean * mean;
    float inv  = rsqrtf(var + 1e-5f);
    #pragma unroll
    for (int i = 0; i < 4; ++i) {
        int c = threadIdx.x + i * 256;
        yr[c] = (v[i] - mean) * inv * w[c] + b[c];
    }
}

// ---------------- causal depthwise conv + ReLU ----------------
__global__ __launch_bounds__(256)
void conv_kernel(const float* __restrict__ x, float* __restrict__ y,
                 const float* __restrict__ cw, const float* __restrict__ cb,
                 int layer, int h0)
{
    const int S = 1024;
    int h  = blockIdx.z;
    int hg = h0 + h;
    int q0 = blockIdx.y * 64;
    int k0 = blockIdx.x * 64;
    __shared__ float Ls[126][64];
    __shared__ float ws[63];
    int tid = threadIdx.x;
    if (tid < 63) ws[tid] = cw[(layer * 32 + hg) * 63 + tid];
    float bias = cb[layer * 32 + hg];
    int c  = tid & 63;
    int r0 = tid >> 6;
    const float* xh = x + (long)h * S * S;
    for (int r = r0; r < 126; r += 4) {
        int g = q0 - 62 + r;
        Ls[r][c] = (g >= 0) ? xh[(long)g * S + k0 + c] : 0.f;
    }
    __syncthreads();
    float* yh = y + (long)h * S * S;
    #pragma unroll 1
    for (int qi = r0; qi < 64; qi += 4) {
        float acc = bias;
        #pragma unroll
        for (int t = 0; t < 63; ++t)
            acc += ws[t] * Ls[qi + t][c];
        yh[(long)(q0 + qi) * S + k0 + c] = fmaxf(acc, 0.f);
    }
}

// ---------------- fused LayerNorm2 + mask + softmax + sigmoid gate -> bf16 p ----------------
__global__ __launch_bounds__(256)
void ln2_softmax(const float* __restrict__ x, __hip_bfloat16* __restrict__ pb,
                 const float* __restrict__ w, const float* __restrict__ b,
                 const float* __restrict__ mask, const float* __restrict__ est)
{
    const int S = 1024;
    long row = blockIdx.x;
    int q = (int)(row & (S - 1));
    const float* xr = x + row * 1024;
    const float* mrow = mask + (long)q * S;
    __shared__ float sb[8];
    float v[4];
    float s = 0.f, ss = 0.f;
    #pragma unroll
    for (int i = 0; i < 4; ++i) {
        int c = threadIdx.x + i * 256;
        v[i] = xr[c];
        s += v[i]; ss += v[i] * v[i];
    }
    #pragma unroll
    for (int off = 32; off; off >>= 1) {
        s  += __shfl_down(s, off, 64);
        ss += __shfl_down(ss, off, 64);
    }
    int wid = threadIdx.x >> 6, lane = threadIdx.x & 63;
    if (!lane) { sb[wid] = s; sb[4 + wid] = ss; }
    __syncthreads();
    s  = sb[0] + sb[1] + sb[2] + sb[3];
    ss = sb[4] + sb[5] + sb[6] + sb[7];
    float mean = s * (1.f / 1024.f);
    float var  = ss * (1.f / 1024.f) - mean * mean;
    float inv  = rsqrtf(var + 1e-5f);
    const float FMIN = -3.4028235e38f;
    float mx = FMIN;
    #pragma unroll
    for (int i = 0; i < 4; ++i) {
        int c = threadIdx.x + i * 256;
        float t = (v[i] - mean) * inv * w[c] + b[c] + mrow[c];
        t = fmaxf(t, FMIN);
        v[i] = t;
        mx = fmaxf(mx, t);
    }
    #pragma unroll
    for (int off = 32; off; off >>= 1) mx = fmaxf(mx, __shfl_down(mx, off, 64));
    __syncthreads();
    if (!lane) sb[wid] = mx;
    __syncthreads();
    mx = fmaxf(fmaxf(sb[0], sb[1]), fmaxf(sb[2], sb[3]));
    float s2 = 0.f;
    #pragma unroll
    for (int i = 0; i < 4; ++i) { v[i] = expf(v[i] - mx); s2 += v[i]; }
    #pragma unroll
    for (int off = 32; off; off >>= 1) s2 += __shfl_down(s2, off, 64);
    __syncthreads();
    if (!lane) sb[4 + wid] = s2;
    __syncthreads();
    s2 = sb[4] + sb[5] + sb[6] + sb[7];
    float e = est[row];
    float sc = (1.f / (1.f + expf(-e))) / s2;
    __hip_bfloat16* pr = pb + row * S;
    #pragma unroll
    for (int i = 0; i < 4; ++i) {
        int c = threadIdx.x + i * 256;
        pr[c] = __float2bfloat16(v[i] * sc);
    }
}

extern "C" void kernel_launch(void* const* d_in, const int* in_sizes, int n_in,
                              void* d_out, int out_size, void* d_ws, size_t ws_size,
                              hipStream_t stream) {
    const int S = 1024, H = 32, HID = 4096, DH = 128, DL = 64;

    const float* hs   = (const float*)d_in[0];
    const float* mask = (const float*)d_in[1];
    const int*   pos  = (const int*)d_in[2];
    const float* Wq   = (const float*)d_in[3];
    const float* Wk   = (const float*)d_in[4];
    const float* Wv   = (const float*)d_in[5];
    const float* Wo   = (const float*)d_in[6];
    const float* Wdq  = (const float*)d_in[7];
    const float* Wdk  = (const float*)d_in[8];
    const float* ln1w = (const float*)d_in[9];
    const float* ln1b = (const float*)d_in[10];
    const float* ln2w = (const float*)d_in[11];
    const float* ln2b = (const float*)d_in[12];
    const float* cw   = (const float*)d_in[13];
    const float* cb   = (const float*)d_in[14];
    const float* sw   = (const float*)d_in[15];
    const float* sbia = (const float*)d_in[16];
    float* out = (float*)d_out;

    // ---- workspace layout (floats) ----
    float* p   = (float*)d_ws;
    float* qb  = p; p += (long)S * HID;          // q fp32; later ao (PV out)
    float* kb  = p; p += (long)S * HID;          // k fp32
    float* ql  = p; p += (long)H * S * DL;       // fp32
    float* kl  = p; p += (long)H * S * DL;
    float* est = p; p += (long)H * S;
    short* hsH = (short*)p; p += (long)S * HID / 2;   // bf16 hs hi; later ao_hi
    short* hsL = (short*)p; p += (long)S * HID / 2;   // bf16 hs lo; later vT16
    short* Wb  = (short*)p; p += (long)HID * HID / 2; // bf16 one weight part
    float* ao  = qb;
    short* aoH = hsH;
    short* vT  = hsL;   // [H][128][1024] bf16

    long wsFloats  = (long)(ws_size / 4);
    long usedFixed = p - (float*)d_ws;
    long perHead   = 2L * S * S;                 // sc0 + sc1 fp32
    int CH = (int)((wsFloats - usedFixed) / perHead);
    if (CH > H) CH = H;
    if (CH < 1) CH = 1;
    float* sc0 = p;
    float* sc1 = sc0 + (long)CH * S * S;
    __hip_bfloat16* pb = (__hip_bfloat16*)sc1;   // alias: sc1 dead after conv3

    dim3 blk(256);
    dim3 gProj(HID / 128, S / 128, 1);
    long n4_hs = (long)S * HID / 4, n4_W = (long)HID * HID / 4;

    // hs -> hi/lo bf16
    cvt_part<false><<<2048, blk, 0, stream>>>(hs, hsH, n4_hs);
    cvt_part<true ><<<2048, blk, 0, stream>>>(hs, hsL, n4_hs);

    // ---- Q projection: hi*hi + lo*hi + hi*lo (3-term split) ----
    cvt_part<false><<<2048, blk, 0, stream>>>(Wq, Wb, n4_W);
    gemm16<0><<<gProj, blk, 0, stream>>>((__hip_bfloat16*)hsH, HID, 0, (__hip_bfloat16*)Wb, HID, 0, qb, HID, 0, HID, 1.f);
    gemm16<1><<<gProj, blk, 0, stream>>>((__hip_bfloat16*)hsL, HID, 0, (__hip_bfloat16*)Wb, HID, 0, qb, HID, 0, HID, 1.f);
    cvt_part<true ><<<2048, blk, 0, stream>>>(Wq, Wb, n4_W);
    gemm16<1><<<gProj, blk, 0, stream>>>((__hip_bfloat16*)hsH, HID, 0, (__hip_bfloat16*)Wb, HID, 0, qb, HID, 0, HID, 1.f);

    // ---- K projection ----
    cvt_part<false><<<2048, blk, 0, stream>>>(Wk, Wb, n4_W);
    gemm16<0><<<gProj, blk, 0, stream>>>((__hip_bfloat16*)hsH, HID, 0, (__hip_bfloat16*)Wb, HID, 0, kb, HID, 0, HID, 1.f);
    gemm16<1><<<gProj, blk, 0, stream>>>((__hip_bfloat16*)hsL, HID, 0, (__hip_bfloat16*)Wb, HID, 0, kb, HID, 0, HID, 1.f);
    cvt_part<true ><<<2048, blk, 0, stream>>>(Wk, Wb, n4_W);
    gemm16<1><<<gProj, blk, 0, stream>>>((__hip_bfloat16*)hsH, HID, 0, (__hip_bfloat16*)Wb, HID, 0, kb, HID, 0, HID, 1.f);

    // ---- V projection: hi-only, write vT bf16 [H][128][1024] directly (hsL now dead) ----
    cvt_part<false><<<2048, blk, 0, stream>>>(Wv, Wb, n4_W);
    gemm16<2><<<gProj, blk, 0, stream>>>((__hip_bfloat16*)hsH, HID, 0, (__hip_bfloat16*)Wb, HID, 0, vT, S, 0, HID, 1.f);

    rope_kernel<<<(S * H * 64 + 255) / 256, blk, 0, stream>>>(qb, kb, pos);

    // low-rank down-proj (fp32 VALU, exact)
    gemm_f32<true><<<dim3(1, S / 64, H), blk, 0, stream>>>(qb, HID, 128, Wdq, DH, 0, ql, DL, (long)S * DL, S, DL, DH, 1.f);
    gemm_f32<true><<<dim3(1, S / 64, H), blk, 0, stream>>>(kb, HID, 128, Wdk, DH, 0, kl, DL, (long)S * DL, S, DL, DH, 1.f);

    for (int c0 = 0; c0 < H; c0 += CH) {
        int ch = (c0 + CH <= H) ? CH : (H - c0);
        // scores = ql.kl^T / 8  (in-register 3-term split)
        gemm_s<<<dim3(S / 128, S / 128, ch), blk, 0, stream>>>(
            ql + (long)c0 * S * DL, DL, (long)S * DL,
            kl + (long)c0 * S * DL, DL, (long)S * DL,
            sc0, S, (long)S * S, DL, 0.125f);
        est_ln1<<<ch * S, blk, 0, stream>>>(sc0, sc1, sw, sbia, est + (long)c0 * S, ln1w, ln1b);
        conv_kernel<<<dim3(16, 16, ch), blk, 0, stream>>>(sc1, sc0, cw, cb, 0, c0);
        conv_kernel<<<dim3(16, 16, ch), blk, 0, stream>>>(sc0, sc1, cw, cb, 1, c0);
        conv_kernel<<<dim3(16, 16, ch), blk, 0, stream>>>(sc1, sc0, cw, cb, 2, c0);
        ln2_softmax<<<ch * S, blk, 0, stream>>>(sc0, pb, ln2w, ln2b, mask, est + (long)c0 * S);
        // out_h = p @ v : bf16 MFMA, B = vT rows (h*128+d)
        gemm16<0><<<dim3(1, S / 128, ch), blk, 0, stream>>>(
            (__hip_bfloat16*)pb, S, (long)S * S,
            (__hip_bfloat16*)(vT + (long)c0 * DH * S), S, (long)DH * S,
            ao + (long)c0 * 128, HID, 128,
            S, 1.f);
    }

    // ---- final: out = ao @ Wo^T (hi-only bf16) ----
    cvt_part<false><<<2048, blk, 0, stream>>>(ao, aoH, n4_hs);
    cvt_part<false><<<2048, blk, 0, stream>>>(Wo, Wb, n4_W);
    gemm16<0><<<gProj, blk, 0, stream>>>((__hip_bfloat16*)aoH, HID, 0, (__hip_bfloat16*)Wb, HID, 0, out, HID, 0, HID, 1.f);
}

// Round 6
// 1380.576 us; speedup vs baseline: 2.4583x; 1.4774x over previous
//
#include <hip/hip_runtime.h>
#include <hip/hip_bf16.h>

typedef __attribute__((ext_vector_type(8))) short bf16x8;
typedef __attribute__((ext_vector_type(4))) float f32x4;

#define TILE 64
#define TK 16

// round-to-nearest-even f32 -> bf16 bits
__device__ inline short f2bf(float x) {
    unsigned u = __float_as_uint(x);
    unsigned r = (u + 0x7fffu + ((u >> 16) & 1u)) >> 16;
    return (short)r;
}
__device__ inline float bf2f(short h) {
    return __uint_as_float(((unsigned)(unsigned short)h) << 16);
}

// ---------------- fp32 VALU GEMM (down-proj only): C = A * B^T ----------------
template<bool BT>
__global__ __launch_bounds__(256)
void gemm_f32(const float* __restrict__ A, int lda, long sA,
              const float* __restrict__ B, int ldb, long sB,
              float* __restrict__ C, int ldc, long sC,
              int M, int N, int Kd, float alpha)
{
    long bz = blockIdx.z;
    A += bz * sA; B += bz * sB; C += bz * sC;
    int m0 = blockIdx.y * TILE, n0 = blockIdx.x * TILE;
    __shared__ float As[TK][TILE + 4];
    __shared__ float Bs[TK][TILE + 4];
    int tid = threadIdx.x;
    int tm = (tid >> 4) * 4;
    int tn = (tid & 15) * 4;
    float acc[4][4] = {};
    for (int k0 = 0; k0 < Kd; k0 += TK) {
        {
            int kk = tid & 15;
            int m  = tid >> 4;
            #pragma unroll
            for (int mm = 0; mm < 4; ++mm)
                As[kk][m + mm * 16] = A[(long)(m0 + m + mm * 16) * lda + k0 + kk];
        }
        {
            int kk = tid & 15;
            int n  = tid >> 4;
            #pragma unroll
            for (int nn = 0; nn < 4; ++nn)
                Bs[kk][n + nn * 16] = B[(long)(n0 + n + nn * 16) * ldb + k0 + kk];
        }
        __syncthreads();
        #pragma unroll
        for (int kk = 0; kk < TK; ++kk) {
            float4 a4 = *reinterpret_cast<const float4*>(&As[kk][tm]);
            float4 b4 = *reinterpret_cast<const float4*>(&Bs[kk][tn]);
            float a[4] = {a4.x, a4.y, a4.z, a4.w};
            float b[4] = {b4.x, b4.y, b4.z, b4.w};
            #pragma unroll
            for (int i = 0; i < 4; ++i)
                #pragma unroll
                for (int j = 0; j < 4; ++j)
                    acc[i][j] += a[i] * b[j];
        }
        __syncthreads();
    }
    #pragma unroll
    for (int i = 0; i < 4; ++i)
        #pragma unroll
        for (int j = 0; j < 4; ++j)
            C[(long)(m0 + tm + i) * ldc + n0 + tn + j] = alpha * acc[i][j];
}

// ---------------- m97-style bf16 MFMA GEMM: C (+)= alpha * A * B^T ----------------
// CMODE 0: C fp32 =, 1: C fp32 +=, 2: C^T bf16 (CT[n][m])
__device__ inline void gld_lds16(const __hip_bfloat16* g, __hip_bfloat16* l)
{
    __builtin_amdgcn_global_load_lds(
        (const __attribute__((address_space(1))) unsigned int*)g,
        (__attribute__((address_space(3))) unsigned int*)l,
        16, 0, 0);
}

template<int CMODE>
__global__ __launch_bounds__(256)
void gemm16(const __hip_bfloat16* __restrict__ A, int lda, long sA,
            const __hip_bfloat16* __restrict__ B, int ldb, long sB,
            void* __restrict__ Cv, int ldc, long sC,
            int Kd, float alpha)
{
    __shared__ __hip_bfloat16 As[128][32];
    __shared__ __hip_bfloat16 Bs[128][32];
    long bz = blockIdx.z;
    A += bz * sA; B += bz * sB;
    int m0 = blockIdx.y * 128, n0 = blockIdx.x * 128;
    int tid  = threadIdx.x;
    int w    = tid >> 6, lane = tid & 63;
    int wm   = w >> 1,  wn   = w & 1;
    int lrow = lane >> 2;
    int lseg = (lane & 3) * 8;
    int fr   = lane & 15;
    int kg   = (lane >> 4) * 8;
    f32x4 acc[4][4] = {};
    for (int k0 = 0; k0 < Kd; k0 += 32) {
        #pragma unroll
        for (int i = 0; i < 2; ++i) {
            int r = w * 32 + i * 16;
            gld_lds16(&A[(long)(m0 + r + lrow) * lda + k0 + lseg], &As[r][0]);
            gld_lds16(&B[(long)(n0 + r + lrow) * ldb + k0 + lseg], &Bs[r][0]);
        }
        __syncthreads();
        bf16x8 af[4], bfr[4];
        #pragma unroll
        for (int m = 0; m < 4; ++m)
            af[m] = *(const bf16x8*)&As[wm * 64 + m * 16 + fr][kg];
        #pragma unroll
        for (int n = 0; n < 4; ++n)
            bfr[n] = *(const bf16x8*)&Bs[wn * 64 + n * 16 + fr][kg];
        #pragma unroll
        for (int m = 0; m < 4; ++m)
            #pragma unroll
            for (int n = 0; n < 4; ++n)
                acc[m][n] = __builtin_amdgcn_mfma_f32_16x16x32_bf16(af[m], bfr[n], acc[m][n], 0, 0, 0);
        __syncthreads();
    }
    int crow0 = (lane >> 4) * 4;
    if constexpr (CMODE == 2) {
        __hip_bfloat16* CT = (__hip_bfloat16*)Cv + bz * sC;
        #pragma unroll
        for (int m = 0; m < 4; ++m)
            #pragma unroll
            for (int n = 0; n < 4; ++n)
                #pragma unroll
                for (int r = 0; r < 4; ++r) {
                    int row = m0 + wm * 64 + m * 16 + crow0 + r;
                    int col = n0 + wn * 64 + n * 16 + fr;
                    CT[(long)col * ldc + row] = __float2bfloat16(alpha * acc[m][n][r]);
                }
    } else {
        float* C = (float*)Cv + bz * sC;
        #pragma unroll
        for (int m = 0; m < 4; ++m)
            #pragma unroll
            for (int n = 0; n < 4; ++n)
                #pragma unroll
                for (int r = 0; r < 4; ++r) {
                    long idx = (long)(m0 + wm * 64 + m * 16 + crow0 + r) * ldc
                             + n0 + wn * 64 + n * 16 + fr;
                    float v = alpha * acc[m][n][r];
                    if constexpr (CMODE == 1) v += C[idx];
                    C[idx] = v;
                }
    }
}

// ---------------- in-register split MFMA GEMM (QK^T): C = alpha * A * B^T ----------------
#define LP 40
__global__ __launch_bounds__(256)
void gemm_s(const float* __restrict__ A, int lda, long sA,
            const float* __restrict__ B, int ldb, long sB,
            float* __restrict__ C, int ldc, long sC,
            int Kd, float alpha)
{
    __shared__ short Ah[128][LP];
    __shared__ short Bh[128][LP];
    __shared__ short Al[128][LP];
    __shared__ short Bl[128][LP];
    long bz = blockIdx.z;
    A += bz * sA; B += bz * sB; C += bz * sC;
    int m0 = blockIdx.y * 128, n0 = blockIdx.x * 128;
    int tid  = threadIdx.x;
    int lane = tid & 63;
    int w    = tid >> 6;
    int wm   = w >> 1, wn = w & 1;
    int srow = tid >> 1;
    int scol = (tid & 1) * 16;
    int fr   = lane & 15;
    int kg   = (lane >> 4) * 8;
    f32x4 acc[4][4] = {};
    for (int k0 = 0; k0 < Kd; k0 += 32) {
        #pragma unroll
        for (int ab = 0; ab < 2; ++ab) {
            const float* src = ab ? (B + (long)(n0 + srow) * ldb + k0 + scol)
                                  : (A + (long)(m0 + srow) * lda + k0 + scol);
            short* dh = ab ? &Bh[srow][scol] : &Ah[srow][scol];
            short* dl = ab ? &Bl[srow][scol] : &Al[srow][scol];
            #pragma unroll
            for (int half = 0; half < 2; ++half) {
                float4 x0 = *reinterpret_cast<const float4*>(src + half * 8);
                float4 x1 = *reinterpret_cast<const float4*>(src + half * 8 + 4);
                float xs[8] = {x0.x, x0.y, x0.z, x0.w, x1.x, x1.y, x1.z, x1.w};
                bf16x8 hv, lv;
                #pragma unroll
                for (int j = 0; j < 8; ++j) {
                    short hb = f2bf(xs[j]);
                    hv[j] = hb;
                    lv[j] = f2bf(xs[j] - bf2f(hb));
                }
                *reinterpret_cast<bf16x8*>(dh + half * 8) = hv;
                *reinterpret_cast<bf16x8*>(dl + half * 8) = lv;
            }
        }
        __syncthreads();
        bf16x8 afh[4], bfh[4], afl[4], bfl[4];
        #pragma unroll
        for (int m = 0; m < 4; ++m) {
            afh[m] = *(const bf16x8*)&Ah[wm * 64 + m * 16 + fr][kg];
            afl[m] = *(const bf16x8*)&Al[wm * 64 + m * 16 + fr][kg];
        }
        #pragma unroll
        for (int n = 0; n < 4; ++n) {
            bfh[n] = *(const bf16x8*)&Bh[wn * 64 + n * 16 + fr][kg];
            bfl[n] = *(const bf16x8*)&Bl[wn * 64 + n * 16 + fr][kg];
        }
        #pragma unroll
        for (int m = 0; m < 4; ++m)
            #pragma unroll
            for (int n = 0; n < 4; ++n) {
                acc[m][n] = __builtin_amdgcn_mfma_f32_16x16x32_bf16(afh[m], bfh[n], acc[m][n], 0, 0, 0);
                acc[m][n] = __builtin_amdgcn_mfma_f32_16x16x32_bf16(afh[m], bfl[n], acc[m][n], 0, 0, 0);
                acc[m][n] = __builtin_amdgcn_mfma_f32_16x16x32_bf16(afl[m], bfh[n], acc[m][n], 0, 0, 0);
            }
        __syncthreads();
    }
    int crow0 = (lane >> 4) * 4;
    #pragma unroll
    for (int m = 0; m < 4; ++m)
        #pragma unroll
        for (int n = 0; n < 4; ++n)
            #pragma unroll
            for (int r = 0; r < 4; ++r)
                C[(long)(m0 + wm * 64 + m * 16 + crow0 + r) * ldc
                  + n0 + wn * 64 + n * 16 + fr] = alpha * acc[m][n][r];
}

// ---------------- f32 -> bf16 hi or lo part (n4 = n/4) ----------------
struct alignas(8) s4 { short a, b, c, d; };
template<bool LO>
__global__ __launch_bounds__(256)
void cvt_part(const float* __restrict__ x, short* __restrict__ y, long n4)
{
    long i = (long)blockIdx.x * 256 + threadIdx.x;
    long stride = (long)gridDim.x * 256;
    for (; i < n4; i += stride) {
        float4 v = reinterpret_cast<const float4*>(x)[i];
        float xs[4] = {v.x, v.y, v.z, v.w};
        s4 o;
        short* op = &o.a;
        #pragma unroll
        for (int j = 0; j < 4; ++j) {
            short hb = f2bf(xs[j]);
            op[j] = LO ? f2bf(xs[j] - bf2f(hb)) : hb;
        }
        reinterpret_cast<s4*>(y)[i] = o;
    }
}

// ---------------- f32 -> bf16 hi AND lo in one pass ----------------
__global__ __launch_bounds__(256)
void cvt_both(const float* __restrict__ x, short* __restrict__ yh,
              short* __restrict__ yl, long n4)
{
    long i = (long)blockIdx.x * 256 + threadIdx.x;
    long stride = (long)gridDim.x * 256;
    for (; i < n4; i += stride) {
        float4 v = reinterpret_cast<const float4*>(x)[i];
        float xs[4] = {v.x, v.y, v.z, v.w};
        s4 oh, ol;
        short* hp = &oh.a; short* lp = &ol.a;
        #pragma unroll
        for (int j = 0; j < 4; ++j) {
            short hb = f2bf(xs[j]);
            hp[j] = hb;
            lp[j] = f2bf(xs[j] - bf2f(hb));
        }
        reinterpret_cast<s4*>(yh)[i] = oh;
        reinterpret_cast<s4*>(yl)[i] = ol;
    }
}

// ---------------- RoPE in place on q,k [S][4096] ----------------
__global__ __launch_bounds__(256)
void rope_kernel(float* __restrict__ q, float* __restrict__ k, const int* __restrict__ pos)
{
    int i = blockIdx.x * 256 + threadIdx.x;
    if (i >= 1024 * 32 * 64) return;
    int d   = i & 63;
    int rem = i >> 6;
    int h   = rem & 31;
    int s   = rem >> 5;
    float p = (float)pos[s];
    float inv = exp2f(-(float)d * (13.287712379549449f / 64.0f));
    float ang = p * inv;
    float c = cosf(ang), sn = sinf(ang);
    long base = ((long)s * 4096) + h * 128 + d;
    float x1 = q[base], x2 = q[base + 64];
    q[base]      = x1 * c - x2 * sn;
    q[base + 64] = x2 * c + x1 * sn;
    x1 = k[base]; x2 = k[base + 64];
    k[base]      = x1 * c - x2 * sn;
    k[base + 64] = x2 * c + x1 * sn;
}

// ---------------- fused est + LayerNorm1: sc0 -> sc1, est ----------------
__global__ __launch_bounds__(256)
void est_ln1(const float* __restrict__ x, float* __restrict__ y,
             const float* __restrict__ sw, const float* __restrict__ sbias,
             float* __restrict__ est,
             const float* __restrict__ w, const float* __restrict__ b)
{
    long row = blockIdx.x;
    const float* xr = x + row * 1024;
    float* yr = y + row * 1024;
    __shared__ float sb[12];
    float v[4];
    float s = 0.f, ss = 0.f, dt = 0.f;
    #pragma unroll
    for (int i = 0; i < 4; ++i) {
        int c = threadIdx.x + i * 256;
        v[i] = xr[c];
        s += v[i]; ss += v[i] * v[i]; dt += v[i] * sw[c];
    }
    #pragma unroll
    for (int off = 32; off; off >>= 1) {
        s  += __shfl_down(s, off, 64);
        ss += __shfl_down(ss, off, 64);
        dt += __shfl_down(dt, off, 64);
    }
    int wid = threadIdx.x >> 6, lane = threadIdx.x & 63;
    if (!lane) { sb[wid] = s; sb[4 + wid] = ss; sb[8 + wid] = dt; }
    __syncthreads();
    s  = sb[0] + sb[1] + sb[2] + sb[3];
    ss = sb[4] + sb[5] + sb[6] + sb[7];
    if (threadIdx.x == 0) est[row] = sb[8] + sb[9] + sb[10] + sb[11] + sbias[0];
    float mean = s * (1.f / 1024.f);
    float var  = ss * (1.f / 1024.f) - mean * mean;
    float inv  = rsqrtf(var + 1e-5f);
    #pragma unroll
    for (int i = 0; i < 4; ++i) {
        int c = threadIdx.x + i * 256;
        yr[c] = (v[i] - mean) * inv * w[c] + b[c];
    }
}

// ---------------- causal depthwise conv + ReLU, register-tap version ----------------
// Thread owns column (k0+c) and 16 outputs q in [q0+grp*16, +16). Input window
// X[78] in registers (static indexing); all row loads are wave-coalesced.
__global__ __launch_bounds__(256)
void conv_fast(const float* __restrict__ x, float* __restrict__ y,
               const float* __restrict__ cw, const float* __restrict__ cb,
               int layer, int h0)
{
    const int S = 1024;
    int h  = blockIdx.z;
    int hg = h0 + h;
    int q0 = blockIdx.y * 64;
    int k0 = blockIdx.x * 64;
    __shared__ float ws[63];
    if (threadIdx.x < 63) ws[threadIdx.x] = cw[(layer * 32 + hg) * 63 + threadIdx.x];
    __syncthreads();
    int c   = threadIdx.x & 63;
    int grp = threadIdx.x >> 6;
    int qb  = q0 + grp * 16;
    const float* xh = x + (long)h * S * S + k0 + c;
    float X[78];
    #pragma unroll
    for (int j = 0; j < 78; ++j) {
        int g = qb - 62 + j;
        X[j] = (g >= 0) ? xh[(long)g * S] : 0.f;
    }
    float wr[63];
    #pragma unroll
    for (int t = 0; t < 63; ++t) wr[t] = ws[t];
    float bias = cb[layer * 32 + hg];
    float* yh = y + (long)h * S * S + k0 + c;
    #pragma unroll
    for (int i = 0; i < 16; ++i) {
        float a0 = 0.f, a1 = 0.f, a2 = 0.f, a3 = 0.f;
        #pragma unroll
        for (int t = 0; t < 60; t += 4) {
            a0 += wr[t]     * X[i + t];
            a1 += wr[t + 1] * X[i + t + 1];
            a2 += wr[t + 2] * X[i + t + 2];
            a3 += wr[t + 3] * X[i + t + 3];
        }
        a0 += wr[60] * X[i + 60];
        a1 += wr[61] * X[i + 61];
        a2 += wr[62] * X[i + 62];
        float acc = bias + ((a0 + a1) + (a2 + a3));
        yh[(long)(qb + i) * S] = fmaxf(acc, 0.f);
    }
}

// ---------------- fused LayerNorm2 + mask + softmax + sigmoid gate -> bf16 p ----------------
__global__ __launch_bounds__(256)
void ln2_softmax(const float* __restrict__ x, __hip_bfloat16* __restrict__ pb,
                 const float* __restrict__ w, const float* __restrict__ b,
                 const float* __restrict__ mask, const float* __restrict__ est)
{
    const int S = 1024;
    long row = blockIdx.x;
    int q = (int)(row & (S - 1));
    const float* xr = x + row * 1024;
    const float* mrow = mask + (long)q * S;
    __shared__ float sb[8];
    float v[4];
    float s = 0.f, ss = 0.f;
    #pragma unroll
    for (int i = 0; i < 4; ++i) {
        int c = threadIdx.x + i * 256;
        v[i] = xr[c];
        s += v[i]; ss += v[i] * v[i];
    }
    #pragma unroll
    for (int off = 32; off; off >>= 1) {
        s  += __shfl_down(s, off, 64);
        ss += __shfl_down(ss, off, 64);
    }
    int wid = threadIdx.x >> 6, lane = threadIdx.x & 63;
    if (!lane) { sb[wid] = s; sb[4 + wid] = ss; }
    __syncthreads();
    s  = sb[0] + sb[1] + sb[2] + sb[3];
    ss = sb[4] + sb[5] + sb[6] + sb[7];
    float mean = s * (1.f / 1024.f);
    float var  = ss * (1.f / 1024.f) - mean * mean;
    float inv  = rsqrtf(var + 1e-5f);
    const float FMIN = -3.4028235e38f;
    float mx = FMIN;
    #pragma unroll
    for (int i = 0; i < 4; ++i) {
        int c = threadIdx.x + i * 256;
        float t = (v[i] - mean) * inv * w[c] + b[c] + mrow[c];
        t = fmaxf(t, FMIN);
        v[i] = t;
        mx = fmaxf(mx, t);
    }
    #pragma unroll
    for (int off = 32; off; off >>= 1) mx = fmaxf(mx, __shfl_down(mx, off, 64));
    __syncthreads();
    if (!lane) sb[wid] = mx;
    __syncthreads();
    mx = fmaxf(fmaxf(sb[0], sb[1]), fmaxf(sb[2], sb[3]));
    float s2 = 0.f;
    #pragma unroll
    for (int i = 0; i < 4; ++i) { v[i] = expf(v[i] - mx); s2 += v[i]; }
    #pragma unroll
    for (int off = 32; off; off >>= 1) s2 += __shfl_down(s2, off, 64);
    __syncthreads();
    if (!lane) sb[4 + wid] = s2;
    __syncthreads();
    s2 = sb[4] + sb[5] + sb[6] + sb[7];
    float e = est[row];
    float sc = (1.f / (1.f + expf(-e))) / s2;
    __hip_bfloat16* pr = pb + row * S;
    #pragma unroll
    for (int i = 0; i < 4; ++i) {
        int c = threadIdx.x + i * 256;
        pr[c] = __float2bfloat16(v[i] * sc);
    }
}

extern "C" void kernel_launch(void* const* d_in, const int* in_sizes, int n_in,
                              void* d_out, int out_size, void* d_ws, size_t ws_size,
                              hipStream_t stream) {
    const int S = 1024, H = 32, HID = 4096, DH = 128, DL = 64;

    const float* hs   = (const float*)d_in[0];
    const float* mask = (const float*)d_in[1];
    const int*   pos  = (const int*)d_in[2];
    const float* Wq   = (const float*)d_in[3];
    const float* Wk   = (const float*)d_in[4];
    const float* Wv   = (const float*)d_in[5];
    const float* Wo   = (const float*)d_in[6];
    const float* Wdq  = (const float*)d_in[7];
    const float* Wdk  = (const float*)d_in[8];
    const float* ln1w = (const float*)d_in[9];
    const float* ln1b = (const float*)d_in[10];
    const float* ln2w = (const float*)d_in[11];
    const float* ln2b = (const float*)d_in[12];
    const float* cw   = (const float*)d_in[13];
    const float* cb   = (const float*)d_in[14];
    const float* sw   = (const float*)d_in[15];
    const float* sbia = (const float*)d_in[16];
    float* out = (float*)d_out;

    // ---- workspace layout (floats) ----
    float* p   = (float*)d_ws;
    float* qb  = p; p += (long)S * HID;          // q fp32; later ao (PV out)
    float* kb  = p; p += (long)S * HID;          // k fp32
    float* ql  = p; p += (long)H * S * DL;
    float* kl  = p; p += (long)H * S * DL;
    float* est = p; p += (long)H * S;
    short* hsH = (short*)p; p += (long)S * HID / 2;   // bf16 hs hi; later ao_hi
    short* hsL = (short*)p; p += (long)S * HID / 2;   // bf16 hs lo; later vT16
    short* Wb  = (short*)p; p += (long)HID * HID / 2; // bf16 weight hi
    short* WbL = (short*)p; p += (long)HID * HID / 2; // bf16 weight lo
    float* ao  = qb;
    short* aoH = hsH;
    short* vT  = hsL;   // [H][128][1024] bf16

    long wsFloats  = (long)(ws_size / 4);
    long usedFixed = p - (float*)d_ws;
    long perHead   = 2L * S * S;                 // sc0 + sc1 fp32
    int CH = (int)((wsFloats - usedFixed) / perHead);
    if (CH > H) CH = H;
    if (CH < 1) CH = 1;
    float* sc0 = p;
    float* sc1 = sc0 + (long)CH * S * S;
    __hip_bfloat16* pb = (__hip_bfloat16*)sc1;   // alias: sc1 dead after conv3

    dim3 blk(256);
    dim3 gProj(HID / 128, S / 128, 1);
    long n4_hs = (long)S * HID / 4, n4_W = (long)HID * HID / 4;

    // hs -> hi/lo bf16 (single pass)
    cvt_both<<<2048, blk, 0, stream>>>(hs, hsH, hsL, n4_hs);

    // ---- Q projection: hi*hi + lo*hi + hi*lo (3-term split) ----
    cvt_both<<<2048, blk, 0, stream>>>(Wq, Wb, WbL, n4_W);
    gemm16<0><<<gProj, blk, 0, stream>>>((__hip_bfloat16*)hsH, HID, 0, (__hip_bfloat16*)Wb, HID, 0, qb, HID, 0, HID, 1.f);
    gemm16<1><<<gProj, blk, 0, stream>>>((__hip_bfloat16*)hsL, HID, 0, (__hip_bfloat16*)Wb, HID, 0, qb, HID, 0, HID, 1.f);
    gemm16<1><<<gProj, blk, 0, stream>>>((__hip_bfloat16*)hsH, HID, 0, (__hip_bfloat16*)WbL, HID, 0, qb, HID, 0, HID, 1.f);

    // ---- K projection ----
    cvt_both<<<2048, blk, 0, stream>>>(Wk, Wb, WbL, n4_W);
    gemm16<0><<<gProj, blk, 0, stream>>>((__hip_bfloat16*)hsH, HID, 0, (__hip_bfloat16*)Wb, HID, 0, kb, HID, 0, HID, 1.f);
    gemm16<1><<<gProj, blk, 0, stream>>>((__hip_bfloat16*)hsL, HID, 0, (__hip_bfloat16*)Wb, HID, 0, kb, HID, 0, HID, 1.f);
    gemm16<1><<<gProj, blk, 0, stream>>>((__hip_bfloat16*)hsH, HID, 0, (__hip_bfloat16*)WbL, HID, 0, kb, HID, 0, HID, 1.f);

    // ---- V projection: hi-only, write vT bf16 [H][128][1024] directly ----
    cvt_part<false><<<2048, blk, 0, stream>>>(Wv, Wb, n4_W);
    gemm16<2><<<gProj, blk, 0, stream>>>((__hip_bfloat16*)hsH, HID, 0, (__hip_bfloat16*)Wb, HID, 0, vT, S, 0, HID, 1.f);

    rope_kernel<<<(S * H * 64 + 255) / 256, blk, 0, stream>>>(qb, kb, pos);

    // low-rank down-proj (fp32 VALU, exact)
    gemm_f32<true><<<dim3(1, S / 64, H), blk, 0, stream>>>(qb, HID, 128, Wdq, DH, 0, ql, DL, (long)S * DL, S, DL, DH, 1.f);
    gemm_f32<true><<<dim3(1, S / 64, H), blk, 0, stream>>>(kb, HID, 128, Wdk, DH, 0, kl, DL, (long)S * DL, S, DL, DH, 1.f);

    for (int c0 = 0; c0 < H; c0 += CH) {
        int ch = (c0 + CH <= H) ? CH : (H - c0);
        // scores = ql.kl^T / 8  (in-register 3-term split)
        gemm_s<<<dim3(S / 128, S / 128, ch), blk, 0, stream>>>(
            ql + (long)c0 * S * DL, DL, (long)S * DL,
            kl + (long)c0 * S * DL, DL, (long)S * DL,
            sc0, S, (long)S * S, DL, 0.125f);
        est_ln1<<<ch * S, blk, 0, stream>>>(sc0, sc1, sw, sbia, est + (long)c0 * S, ln1w, ln1b);
        conv_fast<<<dim3(16, 16, ch), blk, 0, stream>>>(sc1, sc0, cw, cb, 0, c0);
        conv_fast<<<dim3(16, 16, ch), blk, 0, stream>>>(sc0, sc1, cw, cb, 1, c0);
        conv_fast<<<dim3(16, 16, ch), blk, 0, stream>>>(sc1, sc0, cw, cb, 2, c0);
        ln2_softmax<<<ch * S, blk, 0, stream>>>(sc0, pb, ln2w, ln2b, mask, est + (long)c0 * S);
        // out_h = p @ v : bf16 MFMA, B = vT rows (h*128+d)
        gemm16<0><<<dim3(1, S / 128, ch), blk, 0, stream>>>(
            (__hip_bfloat16*)pb, S, (long)S * S,
            (__hip_bfloat16*)(vT + (long)c0 * DH * S), S, (long)DH * S,
            ao + (long)c0 * 128, HID, 128,
            S, 1.f);
    }

    // ---- final: out = ao @ Wo^T (hi-only bf16) ----
    cvt_part<false><<<2048, blk, 0, stream>>>(ao, aoH, n4_hs);
    cvt_part<false><<<2048, blk, 0, stream>>>(Wo, Wb, n4_W);
    gemm16<0><<<gProj, blk, 0, stream>>>((__hip_bfloat16*)aoH, HID, 0, (__hip_bfloat16*)Wb, HID, 0, out, HID, 0, HID, 1.f);
}

// Round 7
// 1147.303 us; speedup vs baseline: 2.9581x; 1.2033x over previous
//
#include <hip/hip_runtime.h>
#include <hip/hip_bf16.h>

typedef __attribute__((ext_vector_type(8))) short bf16x8;
typedef __attribute__((ext_vector_type(4))) float f32x4;

#define TILE 64
#define TK 16

// round-to-nearest-even f32 -> bf16 bits
__device__ inline short f2bf(float x) {
    unsigned u = __float_as_uint(x);
    unsigned r = (u + 0x7fffu + ((u >> 16) & 1u)) >> 16;
    return (short)r;
}
__device__ inline float bf2f(short h) {
    return __uint_as_float(((unsigned)(unsigned short)h) << 16);
}

// ---------------- fp32 VALU GEMM (down-proj only): C = A * B^T ----------------
template<bool BT>
__global__ __launch_bounds__(256)
void gemm_f32(const float* __restrict__ A, int lda, long sA,
              const float* __restrict__ B, int ldb, long sB,
              float* __restrict__ C, int ldc, long sC,
              int M, int N, int Kd, float alpha)
{
    long bz = blockIdx.z;
    A += bz * sA; B += bz * sB; C += bz * sC;
    int m0 = blockIdx.y * TILE, n0 = blockIdx.x * TILE;
    __shared__ float As[TK][TILE + 4];
    __shared__ float Bs[TK][TILE + 4];
    int tid = threadIdx.x;
    int tm = (tid >> 4) * 4;
    int tn = (tid & 15) * 4;
    float acc[4][4] = {};
    for (int k0 = 0; k0 < Kd; k0 += TK) {
        {
            int kk = tid & 15;
            int m  = tid >> 4;
            #pragma unroll
            for (int mm = 0; mm < 4; ++mm)
                As[kk][m + mm * 16] = A[(long)(m0 + m + mm * 16) * lda + k0 + kk];
        }
        {
            int kk = tid & 15;
            int n  = tid >> 4;
            #pragma unroll
            for (int nn = 0; nn < 4; ++nn)
                Bs[kk][n + nn * 16] = B[(long)(n0 + n + nn * 16) * ldb + k0 + kk];
        }
        __syncthreads();
        #pragma unroll
        for (int kk = 0; kk < TK; ++kk) {
            float4 a4 = *reinterpret_cast<const float4*>(&As[kk][tm]);
            float4 b4 = *reinterpret_cast<const float4*>(&Bs[kk][tn]);
            float a[4] = {a4.x, a4.y, a4.z, a4.w};
            float b[4] = {b4.x, b4.y, b4.z, b4.w};
            #pragma unroll
            for (int i = 0; i < 4; ++i)
                #pragma unroll
                for (int j = 0; j < 4; ++j)
                    acc[i][j] += a[i] * b[j];
        }
        __syncthreads();
    }
    #pragma unroll
    for (int i = 0; i < 4; ++i)
        #pragma unroll
        for (int j = 0; j < 4; ++j)
            C[(long)(m0 + tm + i) * ldc + n0 + tn + j] = alpha * acc[i][j];
}

// ---------------- m97-style bf16 MFMA GEMM: C (+)= alpha * A * B^T ----------------
// CMODE 0: C fp32 =, 1: C fp32 +=, 2: C^T bf16 (CT[n][m])
__device__ inline void gld_lds16(const __hip_bfloat16* g, __hip_bfloat16* l)
{
    __builtin_amdgcn_global_load_lds(
        (const __attribute__((address_space(1))) unsigned int*)g,
        (__attribute__((address_space(3))) unsigned int*)l,
        16, 0, 0);
}

template<int CMODE>
__global__ __launch_bounds__(256)
void gemm16(const __hip_bfloat16* __restrict__ A, int lda, long sA,
            const __hip_bfloat16* __restrict__ B, int ldb, long sB,
            void* __restrict__ Cv, int ldc, long sC,
            int Kd, float alpha)
{
    __shared__ __hip_bfloat16 As[128][32];
    __shared__ __hip_bfloat16 Bs[128][32];
    long bz = blockIdx.z;
    A += bz * sA; B += bz * sB;
    int m0 = blockIdx.y * 128, n0 = blockIdx.x * 128;
    int tid  = threadIdx.x;
    int w    = tid >> 6, lane = tid & 63;
    int wm   = w >> 1,  wn   = w & 1;
    int lrow = lane >> 2;
    int lseg = (lane & 3) * 8;
    int fr   = lane & 15;
    int kg   = (lane >> 4) * 8;
    f32x4 acc[4][4] = {};
    for (int k0 = 0; k0 < Kd; k0 += 32) {
        #pragma unroll
        for (int i = 0; i < 2; ++i) {
            int r = w * 32 + i * 16;
            gld_lds16(&A[(long)(m0 + r + lrow) * lda + k0 + lseg], &As[r][0]);
            gld_lds16(&B[(long)(n0 + r + lrow) * ldb + k0 + lseg], &Bs[r][0]);
        }
        __syncthreads();
        bf16x8 af[4], bfr[4];
        #pragma unroll
        for (int m = 0; m < 4; ++m)
            af[m] = *(const bf16x8*)&As[wm * 64 + m * 16 + fr][kg];
        #pragma unroll
        for (int n = 0; n < 4; ++n)
            bfr[n] = *(const bf16x8*)&Bs[wn * 64 + n * 16 + fr][kg];
        #pragma unroll
        for (int m = 0; m < 4; ++m)
            #pragma unroll
            for (int n = 0; n < 4; ++n)
                acc[m][n] = __builtin_amdgcn_mfma_f32_16x16x32_bf16(af[m], bfr[n], acc[m][n], 0, 0, 0);
        __syncthreads();
    }
    int crow0 = (lane >> 4) * 4;
    if constexpr (CMODE == 2) {
        __hip_bfloat16* CT = (__hip_bfloat16*)Cv + bz * sC;
        #pragma unroll
        for (int m = 0; m < 4; ++m)
            #pragma unroll
            for (int n = 0; n < 4; ++n)
                #pragma unroll
                for (int r = 0; r < 4; ++r) {
                    int row = m0 + wm * 64 + m * 16 + crow0 + r;
                    int col = n0 + wn * 64 + n * 16 + fr;
                    CT[(long)col * ldc + row] = __float2bfloat16(alpha * acc[m][n][r]);
                }
    } else {
        float* C = (float*)Cv + bz * sC;
        #pragma unroll
        for (int m = 0; m < 4; ++m)
            #pragma unroll
            for (int n = 0; n < 4; ++n)
                #pragma unroll
                for (int r = 0; r < 4; ++r) {
                    long idx = (long)(m0 + wm * 64 + m * 16 + crow0 + r) * ldc
                             + n0 + wn * 64 + n * 16 + fr;
                    float v = alpha * acc[m][n][r];
                    if constexpr (CMODE == 1) v += C[idx];
                    C[idx] = v;
                }
    }
}

// ---------------- split-K/term bf16 MFMA GEMM with atomic accumulate ----------------
// z selects (term, k-chunk): term = z/chunksPerTerm picks (A0,B0)/(A1,B1)/(A2,B2);
// chunk covers kSteps*32 of K. C must be zeroed before launch; blocks atomicAdd.
__global__ __launch_bounds__(256)
void gemm16_sk(const __hip_bfloat16* __restrict__ A0, const __hip_bfloat16* __restrict__ A1,
               const __hip_bfloat16* __restrict__ A2, int lda,
               const __hip_bfloat16* __restrict__ B0, const __hip_bfloat16* __restrict__ B1,
               const __hip_bfloat16* __restrict__ B2, int ldb,
               float* __restrict__ C, int ldc,
               int kSteps, int chunksPerTerm, float alpha)
{
    __shared__ __hip_bfloat16 As[128][32];
    __shared__ __hip_bfloat16 Bs[128][32];
    int z    = blockIdx.z;
    int term = z / chunksPerTerm;
    int sub  = z - term * chunksPerTerm;
    const __hip_bfloat16* A = (term == 0) ? A0 : (term == 1) ? A1 : A2;
    const __hip_bfloat16* B = (term == 0) ? B0 : (term == 1) ? B1 : B2;
    int kbase = sub * kSteps * 32;
    int m0 = blockIdx.y * 128, n0 = blockIdx.x * 128;
    int tid  = threadIdx.x;
    int w    = tid >> 6, lane = tid & 63;
    int wm   = w >> 1,  wn   = w & 1;
    int lrow = lane >> 2;
    int lseg = (lane & 3) * 8;
    int fr   = lane & 15;
    int kg   = (lane >> 4) * 8;
    f32x4 acc[4][4] = {};
    for (int it = 0; it < kSteps; ++it) {
        int k0 = kbase + it * 32;
        #pragma unroll
        for (int i = 0; i < 2; ++i) {
            int r = w * 32 + i * 16;
            gld_lds16(&A[(long)(m0 + r + lrow) * lda + k0 + lseg], &As[r][0]);
            gld_lds16(&B[(long)(n0 + r + lrow) * ldb + k0 + lseg], &Bs[r][0]);
        }
        __syncthreads();
        bf16x8 af[4], bfr[4];
        #pragma unroll
        for (int m = 0; m < 4; ++m)
            af[m] = *(const bf16x8*)&As[wm * 64 + m * 16 + fr][kg];
        #pragma unroll
        for (int n = 0; n < 4; ++n)
            bfr[n] = *(const bf16x8*)&Bs[wn * 64 + n * 16 + fr][kg];
        #pragma unroll
        for (int m = 0; m < 4; ++m)
            #pragma unroll
            for (int n = 0; n < 4; ++n)
                acc[m][n] = __builtin_amdgcn_mfma_f32_16x16x32_bf16(af[m], bfr[n], acc[m][n], 0, 0, 0);
        __syncthreads();
    }
    int crow0 = (lane >> 4) * 4;
    #pragma unroll
    for (int m = 0; m < 4; ++m)
        #pragma unroll
        for (int n = 0; n < 4; ++n)
            #pragma unroll
            for (int r = 0; r < 4; ++r) {
                long idx = (long)(m0 + wm * 64 + m * 16 + crow0 + r) * ldc
                         + n0 + wn * 64 + n * 16 + fr;
                atomicAdd(&C[idx], alpha * acc[m][n][r]);
            }
}

// ---------------- in-register split MFMA GEMM (QK^T): C = alpha * A * B^T ----------------
#define LP 40
__global__ __launch_bounds__(256)
void gemm_s(const float* __restrict__ A, int lda, long sA,
            const float* __restrict__ B, int ldb, long sB,
            float* __restrict__ C, int ldc, long sC,
            int Kd, float alpha)
{
    __shared__ short Ah[128][LP];
    __shared__ short Bh[128][LP];
    __shared__ short Al[128][LP];
    __shared__ short Bl[128][LP];
    long bz = blockIdx.z;
    A += bz * sA; B += bz * sB; C += bz * sC;
    int m0 = blockIdx.y * 128, n0 = blockIdx.x * 128;
    int tid  = threadIdx.x;
    int lane = tid & 63;
    int w    = tid >> 6;
    int wm   = w >> 1, wn = w & 1;
    int srow = tid >> 1;
    int scol = (tid & 1) * 16;
    int fr   = lane & 15;
    int kg   = (lane >> 4) * 8;
    f32x4 acc[4][4] = {};
    for (int k0 = 0; k0 < Kd; k0 += 32) {
        #pragma unroll
        for (int ab = 0; ab < 2; ++ab) {
            const float* src = ab ? (B + (long)(n0 + srow) * ldb + k0 + scol)
                                  : (A + (long)(m0 + srow) * lda + k0 + scol);
            short* dh = ab ? &Bh[srow][scol] : &Ah[srow][scol];
            short* dl = ab ? &Bl[srow][scol] : &Al[srow][scol];
            #pragma unroll
            for (int half = 0; half < 2; ++half) {
                float4 x0 = *reinterpret_cast<const float4*>(src + half * 8);
                float4 x1 = *reinterpret_cast<const float4*>(src + half * 8 + 4);
                float xs[8] = {x0.x, x0.y, x0.z, x0.w, x1.x, x1.y, x1.z, x1.w};
                bf16x8 hv, lv;
                #pragma unroll
                for (int j = 0; j < 8; ++j) {
                    short hb = f2bf(xs[j]);
                    hv[j] = hb;
                    lv[j] = f2bf(xs[j] - bf2f(hb));
                }
                *reinterpret_cast<bf16x8*>(dh + half * 8) = hv;
                *reinterpret_cast<bf16x8*>(dl + half * 8) = lv;
            }
        }
        __syncthreads();
        bf16x8 afh[4], bfh[4], afl[4], bfl[4];
        #pragma unroll
        for (int m = 0; m < 4; ++m) {
            afh[m] = *(const bf16x8*)&Ah[wm * 64 + m * 16 + fr][kg];
            afl[m] = *(const bf16x8*)&Al[wm * 64 + m * 16 + fr][kg];
        }
        #pragma unroll
        for (int n = 0; n < 4; ++n) {
            bfh[n] = *(const bf16x8*)&Bh[wn * 64 + n * 16 + fr][kg];
            bfl[n] = *(const bf16x8*)&Bl[wn * 64 + n * 16 + fr][kg];
        }
        #pragma unroll
        for (int m = 0; m < 4; ++m)
            #pragma unroll
            for (int n = 0; n < 4; ++n) {
                acc[m][n] = __builtin_amdgcn_mfma_f32_16x16x32_bf16(afh[m], bfh[n], acc[m][n], 0, 0, 0);
                acc[m][n] = __builtin_amdgcn_mfma_f32_16x16x32_bf16(afh[m], bfl[n], acc[m][n], 0, 0, 0);
                acc[m][n] = __builtin_amdgcn_mfma_f32_16x16x32_bf16(afl[m], bfh[n], acc[m][n], 0, 0, 0);
            }
        __syncthreads();
    }
    int crow0 = (lane >> 4) * 4;
    #pragma unroll
    for (int m = 0; m < 4; ++m)
        #pragma unroll
        for (int n = 0; n < 4; ++n)
            #pragma unroll
            for (int r = 0; r < 4; ++r)
                C[(long)(m0 + wm * 64 + m * 16 + crow0 + r) * ldc
                  + n0 + wn * 64 + n * 16 + fr] = alpha * acc[m][n][r];
}

// ---------------- f32 -> bf16 hi or lo part (n4 = n/4) ----------------
struct alignas(8) s4 { short a, b, c, d; };
template<bool LO>
__global__ __launch_bounds__(256)
void cvt_part(const float* __restrict__ x, short* __restrict__ y, long n4)
{
    long i = (long)blockIdx.x * 256 + threadIdx.x;
    long stride = (long)gridDim.x * 256;
    for (; i < n4; i += stride) {
        float4 v = reinterpret_cast<const float4*>(x)[i];
        float xs[4] = {v.x, v.y, v.z, v.w};
        s4 o;
        short* op = &o.a;
        #pragma unroll
        for (int j = 0; j < 4; ++j) {
            short hb = f2bf(xs[j]);
            op[j] = LO ? f2bf(xs[j] - bf2f(hb)) : hb;
        }
        reinterpret_cast<s4*>(y)[i] = o;
    }
}

// ---------------- f32 -> bf16 hi AND lo in one pass ----------------
__global__ __launch_bounds__(256)
void cvt_both(const float* __restrict__ x, short* __restrict__ yh,
              short* __restrict__ yl, long n4)
{
    long i = (long)blockIdx.x * 256 + threadIdx.x;
    long stride = (long)gridDim.x * 256;
    for (; i < n4; i += stride) {
        float4 v = reinterpret_cast<const float4*>(x)[i];
        float xs[4] = {v.x, v.y, v.z, v.w};
        s4 oh, ol;
        short* hp = &oh.a; short* lp = &ol.a;
        #pragma unroll
        for (int j = 0; j < 4; ++j) {
            short hb = f2bf(xs[j]);
            hp[j] = hb;
            lp[j] = f2bf(xs[j] - bf2f(hb));
        }
        reinterpret_cast<s4*>(yh)[i] = oh;
        reinterpret_cast<s4*>(yl)[i] = ol;
    }
}

// ---------------- RoPE in place on q,k [S][4096] ----------------
__global__ __launch_bounds__(256)
void rope_kernel(float* __restrict__ q, float* __restrict__ k, const int* __restrict__ pos)
{
    int i = blockIdx.x * 256 + threadIdx.x;
    if (i >= 1024 * 32 * 64) return;
    int d   = i & 63;
    int rem = i >> 6;
    int h   = rem & 31;
    int s   = rem >> 5;
    float p = (float)pos[s];
    float inv = exp2f(-(float)d * (13.287712379549449f / 64.0f));
    float ang = p * inv;
    float c = cosf(ang), sn = sinf(ang);
    long base = ((long)s * 4096) + h * 128 + d;
    float x1 = q[base], x2 = q[base + 64];
    q[base]      = x1 * c - x2 * sn;
    q[base + 64] = x2 * c + x1 * sn;
    x1 = k[base]; x2 = k[base + 64];
    k[base]      = x1 * c - x2 * sn;
    k[base + 64] = x2 * c + x1 * sn;
}

// ---------------- fused est + LayerNorm1: sc0 -> sc1, est ----------------
__global__ __launch_bounds__(256)
void est_ln1(const float* __restrict__ x, float* __restrict__ y,
             const float* __restrict__ sw, const float* __restrict__ sbias,
             float* __restrict__ est,
             const float* __restrict__ w, const float* __restrict__ b)
{
    long row = blockIdx.x;
    const float* xr = x + row * 1024;
    float* yr = y + row * 1024;
    __shared__ float sb[12];
    float v[4];
    float s = 0.f, ss = 0.f, dt = 0.f;
    #pragma unroll
    for (int i = 0; i < 4; ++i) {
        int c = threadIdx.x + i * 256;
        v[i] = xr[c];
        s += v[i]; ss += v[i] * v[i]; dt += v[i] * sw[c];
    }
    #pragma unroll
    for (int off = 32; off; off >>= 1) {
        s  += __shfl_down(s, off, 64);
        ss += __shfl_down(ss, off, 64);
        dt += __shfl_down(dt, off, 64);
    }
    int wid = threadIdx.x >> 6, lane = threadIdx.x & 63;
    if (!lane) { sb[wid] = s; sb[4 + wid] = ss; sb[8 + wid] = dt; }
    __syncthreads();
    s  = sb[0] + sb[1] + sb[2] + sb[3];
    ss = sb[4] + sb[5] + sb[6] + sb[7];
    if (threadIdx.x == 0) est[row] = sb[8] + sb[9] + sb[10] + sb[11] + sbias[0];
    float mean = s * (1.f / 1024.f);
    float var  = ss * (1.f / 1024.f) - mean * mean;
    float inv  = rsqrtf(var + 1e-5f);
    #pragma unroll
    for (int i = 0; i < 4; ++i) {
        int c = threadIdx.x + i * 256;
        yr[c] = (v[i] - mean) * inv * w[c] + b[c];
    }
}

// ---------------- causal depthwise conv + ReLU, register-tap version ----------------
__global__ __launch_bounds__(256)
void conv_fast(const float* __restrict__ x, float* __restrict__ y,
               const float* __restrict__ cw, const float* __restrict__ cb,
               int layer, int h0)
{
    const int S = 1024;
    int h  = blockIdx.z;
    int hg = h0 + h;
    int q0 = blockIdx.y * 64;
    int k0 = blockIdx.x * 64;
    __shared__ float ws[63];
    if (threadIdx.x < 63) ws[threadIdx.x] = cw[(layer * 32 + hg) * 63 + threadIdx.x];
    __syncthreads();
    int c   = threadIdx.x & 63;
    int grp = threadIdx.x >> 6;
    int qb  = q0 + grp * 16;
    const float* xh = x + (long)h * S * S + k0 + c;
    float X[78];
    #pragma unroll
    for (int j = 0; j < 78; ++j) {
        int g = qb - 62 + j;
        X[j] = (g >= 0) ? xh[(long)g * S] : 0.f;
    }
    float wr[63];
    #pragma unroll
    for (int t = 0; t < 63; ++t) wr[t] = ws[t];
    float bias = cb[layer * 32 + hg];
    float* yh = y + (long)h * S * S + k0 + c;
    #pragma unroll
    for (int i = 0; i < 16; ++i) {
        float a0 = 0.f, a1 = 0.f, a2 = 0.f, a3 = 0.f;
        #pragma unroll
        for (int t = 0; t < 60; t += 4) {
            a0 += wr[t]     * X[i + t];
            a1 += wr[t + 1] * X[i + t + 1];
            a2 += wr[t + 2] * X[i + t + 2];
            a3 += wr[t + 3] * X[i + t + 3];
        }
        a0 += wr[60] * X[i + 60];
        a1 += wr[61] * X[i + 61];
        a2 += wr[62] * X[i + 62];
        float acc = bias + ((a0 + a1) + (a2 + a3));
        yh[(long)(qb + i) * S] = fmaxf(acc, 0.f);
    }
}

// ---------------- fused LayerNorm2 + mask + softmax + sigmoid gate -> bf16 p ----------------
__global__ __launch_bounds__(256)
void ln2_softmax(const float* __restrict__ x, __hip_bfloat16* __restrict__ pb,
                 const float* __restrict__ w, const float* __restrict__ b,
                 const float* __restrict__ mask, const float* __restrict__ est)
{
    const int S = 1024;
    long row = blockIdx.x;
    int q = (int)(row & (S - 1));
    const float* xr = x + row * 1024;
    const float* mrow = mask + (long)q * S;
    __shared__ float sb[8];
    float v[4];
    float s = 0.f, ss = 0.f;
    #pragma unroll
    for (int i = 0; i < 4; ++i) {
        int c = threadIdx.x + i * 256;
        v[i] = xr[c];
        s += v[i]; ss += v[i] * v[i];
    }
    #pragma unroll
    for (int off = 32; off; off >>= 1) {
        s  += __shfl_down(s, off, 64);
        ss += __shfl_down(ss, off, 64);
    }
    int wid = threadIdx.x >> 6, lane = threadIdx.x & 63;
    if (!lane) { sb[wid] = s; sb[4 + wid] = ss; }
    __syncthreads();
    s  = sb[0] + sb[1] + sb[2] + sb[3];
    ss = sb[4] + sb[5] + sb[6] + sb[7];
    float mean = s * (1.f / 1024.f);
    float var  = ss * (1.f / 1024.f) - mean * mean;
    float inv  = rsqrtf(var + 1e-5f);
    const float FMIN = -3.4028235e38f;
    float mx = FMIN;
    #pragma unroll
    for (int i = 0; i < 4; ++i) {
        int c = threadIdx.x + i * 256;
        float t = (v[i] - mean) * inv * w[c] + b[c] + mrow[c];
        t = fmaxf(t, FMIN);
        v[i] = t;
        mx = fmaxf(mx, t);
    }
    #pragma unroll
    for (int off = 32; off; off >>= 1) mx = fmaxf(mx, __shfl_down(mx, off, 64));
    __syncthreads();
    if (!lane) sb[wid] = mx;
    __syncthreads();
    mx = fmaxf(fmaxf(sb[0], sb[1]), fmaxf(sb[2], sb[3]));
    float s2 = 0.f;
    #pragma unroll
    for (int i = 0; i < 4; ++i) { v[i] = expf(v[i] - mx); s2 += v[i]; }
    #pragma unroll
    for (int off = 32; off; off >>= 1) s2 += __shfl_down(s2, off, 64);
    __syncthreads();
    if (!lane) sb[4 + wid] = s2;
    __syncthreads();
    s2 = sb[4] + sb[5] + sb[6] + sb[7];
    float e = est[row];
    float sc = (1.f / (1.f + expf(-e))) / s2;
    __hip_bfloat16* pr = pb + row * S;
    #pragma unroll
    for (int i = 0; i < 4; ++i) {
        int c = threadIdx.x + i * 256;
        pr[c] = __float2bfloat16(v[i] * sc);
    }
}

extern "C" void kernel_launch(void* const* d_in, const int* in_sizes, int n_in,
                              void* d_out, int out_size, void* d_ws, size_t ws_size,
                              hipStream_t stream) {
    const int S = 1024, H = 32, HID = 4096, DH = 128, DL = 64;

    const float* hs   = (const float*)d_in[0];
    const float* mask = (const float*)d_in[1];
    const int*   pos  = (const int*)d_in[2];
    const float* Wq   = (const float*)d_in[3];
    const float* Wk   = (const float*)d_in[4];
    const float* Wv   = (const float*)d_in[5];
    const float* Wo   = (const float*)d_in[6];
    const float* Wdq  = (const float*)d_in[7];
    const float* Wdk  = (const float*)d_in[8];
    const float* ln1w = (const float*)d_in[9];
    const float* ln1b = (const float*)d_in[10];
    const float* ln2w = (const float*)d_in[11];
    const float* ln2b = (const float*)d_in[12];
    const float* cw   = (const float*)d_in[13];
    const float* cb   = (const float*)d_in[14];
    const float* sw   = (const float*)d_in[15];
    const float* sbia = (const float*)d_in[16];
    float* out = (float*)d_out;

    // ---- workspace layout (floats) ----
    float* p   = (float*)d_ws;
    float* qb  = p; p += (long)S * HID;          // q fp32; later ao (PV out)
    float* kb  = p; p += (long)S * HID;          // k fp32
    float* ql  = p; p += (long)H * S * DL;
    float* kl  = p; p += (long)H * S * DL;
    float* est = p; p += (long)H * S;
    short* hsH = (short*)p; p += (long)S * HID / 2;   // bf16 hs hi; later ao_hi
    short* hsL = (short*)p; p += (long)S * HID / 2;   // bf16 hs lo; later vT16
    short* Wb  = (short*)p; p += (long)HID * HID / 2; // bf16 weight hi
    short* WbL = (short*)p; p += (long)HID * HID / 2; // bf16 weight lo
    float* ao  = qb;
    short* aoH = hsH;
    short* vT  = hsL;   // [H][128][1024] bf16

    long wsFloats  = (long)(ws_size / 4);
    long usedFixed = p - (float*)d_ws;
    long perHead   = 2L * S * S;                 // sc0 + sc1 fp32
    int CH = (int)((wsFloats - usedFixed) / perHead);
    if (CH > H) CH = H;
    if (CH < 1) CH = 1;
    float* sc0 = p;
    float* sc1 = sc0 + (long)CH * S * S;
    __hip_bfloat16* pb = (__hip_bfloat16*)sc1;   // alias: sc1 dead after conv3

    dim3 blk(256);
    long n4_hs = (long)S * HID / 4, n4_W = (long)HID * HID / 4;
    size_t projBytes = (size_t)S * HID * sizeof(float);

    // hs -> hi/lo bf16 (single pass)
    cvt_both<<<2048, blk, 0, stream>>>(hs, hsH, hsL, n4_hs);

    // ---- Q projection: 3-term split via split-K/term atomic GEMM (z = 3 terms x 2 chunks) ----
    hipMemsetAsync(qb, 0, projBytes, stream);
    cvt_both<<<2048, blk, 0, stream>>>(Wq, Wb, WbL, n4_W);
    gemm16_sk<<<dim3(HID / 128, S / 128, 6), blk, 0, stream>>>(
        (__hip_bfloat16*)hsH, (__hip_bfloat16*)hsL, (__hip_bfloat16*)hsH, HID,
        (__hip_bfloat16*)Wb,  (__hip_bfloat16*)Wb,  (__hip_bfloat16*)WbL, HID,
        qb, HID, 64, 2, 1.f);

    // ---- K projection ----
    hipMemsetAsync(kb, 0, projBytes, stream);
    cvt_both<<<2048, blk, 0, stream>>>(Wk, Wb, WbL, n4_W);
    gemm16_sk<<<dim3(HID / 128, S / 128, 6), blk, 0, stream>>>(
        (__hip_bfloat16*)hsH, (__hip_bfloat16*)hsL, (__hip_bfloat16*)hsH, HID,
        (__hip_bfloat16*)Wb,  (__hip_bfloat16*)Wb,  (__hip_bfloat16*)WbL, HID,
        kb, HID, 64, 2, 1.f);

    // ---- V projection: hi-only, write vT bf16 [H][128][1024] directly ----
    cvt_part<false><<<2048, blk, 0, stream>>>(Wv, Wb, n4_W);
    gemm16<2><<<dim3(HID / 128, S / 128, 1), blk, 0, stream>>>(
        (__hip_bfloat16*)hsH, HID, 0, (__hip_bfloat16*)Wb, HID, 0, vT, S, 0, HID, 1.f);

    rope_kernel<<<(S * H * 64 + 255) / 256, blk, 0, stream>>>(qb, kb, pos);

    // low-rank down-proj (fp32 VALU, exact)
    gemm_f32<true><<<dim3(1, S / 64, H), blk, 0, stream>>>(qb, HID, 128, Wdq, DH, 0, ql, DL, (long)S * DL, S, DL, DH, 1.f);
    gemm_f32<true><<<dim3(1, S / 64, H), blk, 0, stream>>>(kb, HID, 128, Wdk, DH, 0, kl, DL, (long)S * DL, S, DL, DH, 1.f);

    for (int c0 = 0; c0 < H; c0 += CH) {
        int ch = (c0 + CH <= H) ? CH : (H - c0);
        // scores = ql.kl^T / 8  (in-register 3-term split)
        gemm_s<<<dim3(S / 128, S / 128, ch), blk, 0, stream>>>(
            ql + (long)c0 * S * DL, DL, (long)S * DL,
            kl + (long)c0 * S * DL, DL, (long)S * DL,
            sc0, S, (long)S * S, DL, 0.125f);
        est_ln1<<<ch * S, blk, 0, stream>>>(sc0, sc1, sw, sbia, est + (long)c0 * S, ln1w, ln1b);
        conv_fast<<<dim3(16, 16, ch), blk, 0, stream>>>(sc1, sc0, cw, cb, 0, c0);
        conv_fast<<<dim3(16, 16, ch), blk, 0, stream>>>(sc0, sc1, cw, cb, 1, c0);
        conv_fast<<<dim3(16, 16, ch), blk, 0, stream>>>(sc1, sc0, cw, cb, 2, c0);
        ln2_softmax<<<ch * S, blk, 0, stream>>>(sc0, pb, ln2w, ln2b, mask, est + (long)c0 * S);
        // out_h = p @ v : bf16 MFMA, B = vT rows (h*128+d)
        gemm16<0><<<dim3(1, S / 128, ch), blk, 0, stream>>>(
            (__hip_bfloat16*)pb, S, (long)S * S,
            (__hip_bfloat16*)(vT + (long)c0 * DH * S), S, (long)DH * S,
            ao + (long)c0 * 128, HID, 128,
            S, 1.f);
    }

    // ---- final: out = ao @ Wo^T (hi-only bf16, split-K atomic, z=2) ----
    cvt_part<false><<<2048, blk, 0, stream>>>(ao, aoH, n4_hs);
    cvt_part<false><<<2048, blk, 0, stream>>>(Wo, Wb, n4_W);
    hipMemsetAsync(out, 0, projBytes, stream);
    gemm16_sk<<<dim3(HID / 128, S / 128, 2), blk, 0, stream>>>(
        (__hip_bfloat16*)aoH, (__hip_bfloat16*)aoH, (__hip_bfloat16*)aoH, HID,
        (__hip_bfloat16*)Wb,  (__hip_bfloat16*)Wb,  (__hip_bfloat16*)Wb,  HID,
        out, HID, 64, 2, 1.f);
}